// Round 4
// baseline (293.571 us; speedup 1.0000x reference)
//
#include <hip/hip_runtime.h>
#include <hip/hip_bf16.h>
#include <math.h>

#define HW 9216
#define WD 96
#define NC 128

typedef unsigned short u16;
typedef __attribute__((ext_vector_type(8))) short short8;
typedef __attribute__((ext_vector_type(4))) float v4f;

__device__ __forceinline__ int rfl(int v){ return __builtin_amdgcn_readfirstlane(v); }
__device__ __forceinline__ float bu2f(u16 s){ return __uint_as_float(((unsigned)s)<<16); }
__device__ __forceinline__ float aslo(unsigned u){ return __uint_as_float(u<<16); }
__device__ __forceinline__ float ashi(unsigned u){ return __uint_as_float(u & 0xffff0000u); }
__device__ __forceinline__ u16 f2b(float f){ unsigned u = __float_as_uint(f);
  return (u16)((u + 0x7fffu + ((u>>16)&1u))>>16); }

// ---------------- K0: weight prep ----------------
__global__ __launch_bounds__(256) void prep_weights(const float* __restrict__ pw_w,
    const float* __restrict__ off_w, const float* __restrict__ dc_w,
    u16* __restrict__ wpwb, u16* __restrict__ wob, u16* __restrict__ wdcb){
  int t = blockIdx.x*256 + threadIdx.x;
  if (t < 16384) wpwb[t] = f2b(pw_w[t]);
  if (t < 36864){ int o = t/1152, r = t - o*1152; int k = r>>7, c = r&127;
                  wob[t] = (o<18) ? f2b(off_w[(o*128+c)*9+k]) : (u16)0; }
  if (t < 147456){ int o = t/1152, r = t - o*1152; int k = r>>7, c = r&127;
                   wdcb[t] = f2b(dc_w[(o*128+c)*9 + k]); }
}

// ---------------- K1: depthwise 3x3 + bias (NCHW fp32) ----------------
__global__ __launch_bounds__(256) void dw_conv(const float* __restrict__ x,
    const float* __restrict__ w, const float* __restrict__ bias, float* __restrict__ h1){
  int n = blockIdx.x*256 + threadIdx.x;
  int bc = rfl(n / HW);
  int p = n - bc*HW;
  int c = bc & 127;
  int yy = p / WD, xx = p - (p/WD)*WD;
  const float* xc = x + (size_t)bc*HW;
  float acc = bias[c];
  #pragma unroll
  for (int r=0;r<3;r++){
    int y2 = yy + r - 1;
    #pragma unroll
    for (int cc2=0;cc2<3;cc2++){
      int x2 = xx + cc2 - 1;
      if (y2>=0 && y2<96 && x2>=0 && x2<96)
        acc = fmaf(w[c*9 + r*3 + cc2], xc[y2*WD + x2], acc);
    }
  }
  h1[n] = acc;
}

// ---------------- K2: pointwise 1x1 via MFMA ----------------
__global__ __launch_bounds__(256) void pw_mfma(const float* __restrict__ h1,
    const u16* __restrict__ wpwb, const float* __restrict__ pw_b, float* __restrict__ h2){
  __shared__ short Aw[128*136];
  __shared__ short Bw[128*68];
  int blk = blockIdx.x; int row0 = blk*64;
  int b = rfl(row0/HW); int pbase = rfl(row0 - b*HW);
  int t = threadIdx.x;
  #pragma unroll
  for (int i=0;i<8;i++){
    int idx = i*256 + t; int o = idx>>4, seg = idx&15;
    *(short8*)&Aw[o*136 + seg*8] = *(const short8*)(wpwb + o*128 + seg*8);
  }
  #pragma unroll
  for (int i=0;i<8;i++){
    int idx = i*256 + t; int c = idx>>4, seg = idx&15;
    float4 v = *(const float4*)(h1 + (size_t)(b*NC+c)*HW + pbase + seg*4);
    ushort4 pk = make_ushort4(f2b(v.x), f2b(v.y), f2b(v.z), f2b(v.w));
    *(ushort4*)&Bw[c*68 + seg*4] = pk;
  }
  __syncthreads();
  int w = rfl(t>>6); int l = t&63; int q = l>>4; int ln = l&15;
  v4f acc[8];
  #pragma unroll
  for (int mt=0;mt<8;mt++) acc[mt] = (v4f){0.f,0.f,0.f,0.f};
  #pragma unroll
  for (int ks=0;ks<4;ks++){
    short8 bf;
    #pragma unroll
    for (int j=0;j<8;j++) bf[j] = Bw[(ks*32 + q*8 + j)*68 + w*16 + ln];
    #pragma unroll
    for (int mt=0;mt<8;mt++){
      short8 af = *(short8*)&Aw[(mt*16+ln)*136 + ks*32 + q*8];
      acc[mt] = __builtin_amdgcn_mfma_f32_16x16x32_bf16(af, bf, acc[mt], 0,0,0);
    }
  }
  int px = pbase + w*16 + ln;
  #pragma unroll
  for (int mt=0;mt<8;mt++){
    #pragma unroll
    for (int r=0;r<4;r++){
      int o = mt*16 + q*4 + r;
      h2[(size_t)(b*NC+o)*HW + px] = acc[mt][r] + pw_b[o];
    }
  }
}

// ---------------- K3: InstanceNorm stats ----------------
__global__ __launch_bounds__(256) void inorm_stats(const float* __restrict__ h2, float* __restrict__ st){
  int bc = blockIdx.x;
  const float* src = h2 + (size_t)bc*HW;
  float s=0.f, ss=0.f;
  for (int i=threadIdx.x; i<HW; i+=256){ float v=src[i]; s+=v; ss=fmaf(v,v,ss); }
  #pragma unroll
  for (int off=32; off; off>>=1){ s += __shfl_down(s,off); ss += __shfl_down(ss,off); }
  __shared__ float rsm[2][4];
  int wave = threadIdx.x>>6, lane = threadIdx.x&63;
  if (lane==0){ rsm[0][wave]=s; rsm[1][wave]=ss; }
  __syncthreads();
  if (threadIdx.x==0){
    float S = rsm[0][0]+rsm[0][1]+rsm[0][2]+rsm[0][3];
    float SS= rsm[1][0]+rsm[1][1]+rsm[1][2]+rsm[1][3];
    float mu = S * (1.f/9216.f);
    float var = SS * (1.f/9216.f) - mu*mu;
    st[bc*2]   = mu;
    st[bc*2+1] = rsqrtf(var + 1e-5f);
  }
}

// ---------------- K4: dsc (NCHW fp32) + dscT/dscL (NHWC bf16 hi/lo) ----------------
__global__ __launch_bounds__(256) void make_dsc(const float* __restrict__ h2,
    const float* __restrict__ st, float* __restrict__ dsc,
    u16* __restrict__ dscT, u16* __restrict__ dscL){
  int blk = blockIdx.x;
  int pt = blk % 144; int r = blk/144; int ch = r & 1; int b = r >> 1;
  int c0 = ch*64, pbase = pt*64;
  __shared__ float tile[64][65];
  int tr = threadIdx.x >> 2;
  int g  = threadIdx.x & 3;
  int c  = c0 + tr;
  float mu = st[(b*128+c)*2];
  float rs = st[(b*128+c)*2+1];
  const float* src = h2 + (size_t)(b*128+c)*HW + pbase + g*16;
  float* d = dsc + (size_t)(b*128+c)*HW + pbase + g*16;
  #pragma unroll
  for (int i=0;i<4;i++){
    float4 v = *(const float4*)(src + i*4);
    v.x=(v.x-mu)*rs; v.y=(v.y-mu)*rs; v.z=(v.z-mu)*rs; v.w=(v.w-mu)*rs;
    *(float4*)(d + i*4) = v;
    tile[tr][g*16+i*4+0]=v.x; tile[tr][g*16+i*4+1]=v.y;
    tile[tr][g*16+i*4+2]=v.z; tile[tr][g*16+i*4+3]=v.w;
  }
  __syncthreads();
  int pr = tr;
  u16* dt = dscT + ((size_t)b*HW + pbase + pr)*NC + c0 + g*16;
  u16* dl = dscL + ((size_t)b*HW + pbase + pr)*NC + c0 + g*16;
  #pragma unroll
  for (int i=0;i<4;i++){
    float v0 = tile[g*16+i*4+0][pr], v1 = tile[g*16+i*4+1][pr];
    float v2 = tile[g*16+i*4+2][pr], v3 = tile[g*16+i*4+3][pr];
    ushort4 hi = make_ushort4(f2b(v0), f2b(v1), f2b(v2), f2b(v3));
    ushort4 lo = make_ushort4(f2b(v0-bu2f(hi.x)), f2b(v1-bu2f(hi.y)),
                              f2b(v2-bu2f(hi.z)), f2b(v3-bu2f(hi.w)));
    *(ushort4*)(dt + i*4) = hi;
    *(ushort4*)(dl + i*4) = lo;
  }
}

// ---------------- K5: offset conv via MFMA (register-A, K=64 steps) + bilinear precomp ----
__global__ __launch_bounds__(256) void off_mfma(const u16* __restrict__ dscT,
    const u16* __restrict__ dscL, const u16* __restrict__ wob,
    const float* __restrict__ off_b, float4* __restrict__ wg, ushort4* __restrict__ ad){
  __shared__ short Bs[2048];                 // 4 (sub,nt) tiles x 64 lanes x 8
  __shared__ float Po[18*64];
  int blk = blockIdx.x;
  int g = (blk>>3) + 72*(blk&7);             // XCD swizzle
  int b = rfl(g/144); int pbase = rfl(g - (g/144)*144)*64;
  int t = threadIdx.x;
  int l = t&63; int w = rfl(t>>6);
  int ln = l&15, q = l>>4;
  int P = pbase + w*16 + ln;                 // this lane's pixel (A row m=ln)
  int py = P/96, pxx = P - 96*(P/96);
  int ob = (t&15) + ((t>>6)&1)*16;           // B staging o-row
  int subB = t>>7, qB = (t>>4)&3;
  const u16* hib = dscT + (size_t)b*HW*NC;
  const u16* lob = dscL + (size_t)b*HW*NC;
  uint4 h0,h1,l0,l1, wb;
  const uint4 Z = (uint4){0,0,0,0};
  auto prefetch = [&](int s){
    int tap = s>>1; int cb = (s&1)*64;
    int y2 = py + tap/3 - 1, x2 = pxx + tap%3 - 1;
    bool valid = ((unsigned)y2 < 96u) && ((unsigned)x2 < 96u);
    int off = (y2*96 + x2)*NC + cb + q*8;
    h0 = valid ? *(const uint4*)(hib + off)      : Z;
    h1 = valid ? *(const uint4*)(hib + off + 32) : Z;
    l0 = valid ? *(const uint4*)(lob + off)      : Z;
    l1 = valid ? *(const uint4*)(lob + off + 32) : Z;
    wb = *(const uint4*)(wob + ob*1152 + tap*128 + cb + subB*32 + qB*8);
  };
  short8 a0,a1,a2,a3;
  auto take = [&](){
    __builtin_memcpy(&a0,&h0,16); __builtin_memcpy(&a1,&h1,16);
    __builtin_memcpy(&a2,&l0,16); __builtin_memcpy(&a3,&l1,16);
    *(uint4*)&Bs[t*8] = wb;
  };
  v4f acc[2];
  acc[0] = (v4f){0.f,0.f,0.f,0.f}; acc[1] = (v4f){0.f,0.f,0.f,0.f};
  prefetch(0); take();
  __syncthreads();
  #pragma unroll 1
  for (int s=0;s<18;s++){
    if (s<17) prefetch(s+1);
    short8 b00 = *(short8*)&Bs[(0*64+l)*8];
    short8 b01 = *(short8*)&Bs[(1*64+l)*8];
    short8 b10 = *(short8*)&Bs[(2*64+l)*8];
    short8 b11 = *(short8*)&Bs[(3*64+l)*8];
    acc[0] = __builtin_amdgcn_mfma_f32_16x16x32_bf16(a0, b00, acc[0], 0,0,0);
    acc[1] = __builtin_amdgcn_mfma_f32_16x16x32_bf16(a0, b01, acc[1], 0,0,0);
    acc[0] = __builtin_amdgcn_mfma_f32_16x16x32_bf16(a2, b00, acc[0], 0,0,0);
    acc[1] = __builtin_amdgcn_mfma_f32_16x16x32_bf16(a2, b01, acc[1], 0,0,0);
    acc[0] = __builtin_amdgcn_mfma_f32_16x16x32_bf16(a1, b10, acc[0], 0,0,0);
    acc[1] = __builtin_amdgcn_mfma_f32_16x16x32_bf16(a1, b11, acc[1], 0,0,0);
    acc[0] = __builtin_amdgcn_mfma_f32_16x16x32_bf16(a3, b10, acc[0], 0,0,0);
    acc[1] = __builtin_amdgcn_mfma_f32_16x16x32_bf16(a3, b11, acc[1], 0,0,0);
    __syncthreads();
    if (s<17){ take(); __syncthreads(); }
  }
  #pragma unroll
  for (int nt=0;nt<2;nt++){
    int o = nt*16 + ln;
    if (o < 18){
      float obias = off_b[o];
      #pragma unroll
      for (int r=0;r<4;r++) Po[o*64 + w*16 + q*4 + r] = acc[nt][r] + obias;
    }
  }
  __syncthreads();
  #pragma unroll
  for (int i=0;i<3;i++){
    int idx = i*256 + t;
    if (idx < 576){
      int pxl = idx & 63, k = idx >> 6;
      int Pp = pbase + pxl;
      float dy = Po[(2*k)*64 + pxl], dx = Po[(2*k+1)*64 + pxl];
      float ys = (float)(Pp/96 + k/3 - 1) + dy;
      float xs = (float)(Pp%96 + k%3 - 1) + dx;
      float fy0 = floorf(ys), fx0 = floorf(xs);
      float wy = ys - fy0, wx = xs - fx0;
      int y0 = (int)fy0, x0 = (int)fx0;
      int y1 = y0+1, x1 = x0+1;
      float vy0 = (y0>=0 && y0<=95) ? 1.f : 0.f;
      float vy1 = (y1>=0 && y1<=95) ? 1.f : 0.f;
      float vx0 = (x0>=0 && x0<=95) ? 1.f : 0.f;
      float vx1 = (x1>=0 && x1<=95) ? 1.f : 0.f;
      int y0c=min(max(y0,0),95), y1c=min(max(y1,0),95);
      int x0c=min(max(x0,0),95), x1c=min(max(x1,0),95);
      float4 w4;
      w4.x = (1.f-wy)*(1.f-wx)*vy0*vx0;
      w4.y = (1.f-wy)*wx*vy0*vx1;
      w4.z = wy*(1.f-wx)*vy1*vx0;
      w4.w = wy*wx*vy1*vx1;
      int gi = (b*9 + k)*HW + pbase + pxl;
      wg[gi] = w4;
      ad[gi] = make_ushort4((u16)(y0c*WD+x0c), (u16)(y0c*WD+x1c),
                            (u16)(y1c*WD+x0c), (u16)(y1c*WD+x1c));
    }
  }
}

// ---------------- K6: deform conv (register-A sampling, K-split x2, atomic out) ----------
__global__ __launch_bounds__(256) void deform_mfma(const u16* __restrict__ dscT,
    const u16* __restrict__ wdcb, const float* __restrict__ dc_b,
    const float4* __restrict__ wg, const ushort4* __restrict__ ad,
    float* __restrict__ dc_t){
  __shared__ short Bs[4096];                 // 8 nt tiles x 64 lanes x 8
  int blk = blockIdx.x;                      // 1152 = 576 tiles x 2 K-halves
  int base = blk>>1, half = blk&1;
  int g = (base>>3) + 72*(base&7);           // XCD swizzle
  int b = rfl(g/144); int pbase = rfl(g - (g/144)*144)*64;
  int t = threadIdx.x;
  int l = t&63; int w = rfl(t>>6);
  int ln = l&15, q = l>>4;
  int px = w*16 + ln;                        // this lane's pixel (A row m=ln)
  int oa = w*16 + ln;                        // B staging rows oa, oa+64
  int s0 = half*18;
  const u16* db0 = dscT + (size_t)b*HW*NC;
  float4 wv; ushort4 av; uint4 r0,r1,r2,r3, wb0, wb1;
  auto prefetch = [&](int s){
    int k = s>>2; int cs = ((s&3)<<5) + q*8;
    int wgi = (b*9 + k)*HW + pbase + px;
    wv = wg[wgi]; av = ad[wgi];
    const u16* db = db0 + cs;
    r0 = *(const uint4*)(db + (int)av.x*NC);
    r1 = *(const uint4*)(db + (int)av.y*NC);
    r2 = *(const uint4*)(db + (int)av.z*NC);
    r3 = *(const uint4*)(db + (int)av.w*NC);
    const u16* wp = wdcb + s*32 + q*8;
    wb0 = *(const uint4*)(wp + oa*1152);
    wb1 = *(const uint4*)(wp + (oa+64)*1152);
  };
  short8 af;
  auto combine = [&](){
    const unsigned* pa=(const unsigned*)&r0; const unsigned* pb=(const unsigned*)&r1;
    const unsigned* pc=(const unsigned*)&r2; const unsigned* pd=(const unsigned*)&r3;
    unsigned pk[4];
    #pragma unroll
    for (int jp=0;jp<4;jp++){
      float flo = wv.x*aslo(pa[jp]) + wv.y*aslo(pb[jp]) + wv.z*aslo(pc[jp]) + wv.w*aslo(pd[jp]);
      float fhi = wv.x*ashi(pa[jp]) + wv.y*ashi(pb[jp]) + wv.z*ashi(pc[jp]) + wv.w*ashi(pd[jp]);
      __hip_bfloat162 hv = __float22bfloat162_rn(make_float2(flo, fhi));
      unsigned uu; __builtin_memcpy(&uu, &hv, 4);
      pk[jp] = uu;
    }
    __builtin_memcpy(&af, pk, 16);
    *(uint4*)&Bs[t*8] = wb0;
    *(uint4*)&Bs[2048 + t*8] = wb1;
  };
  v4f acc[8];
  #pragma unroll
  for (int nt=0;nt<8;nt++) acc[nt] = (v4f){0.f,0.f,0.f,0.f};
  prefetch(s0); combine();
  __syncthreads();
  #pragma unroll 1
  for (int s=0;s<18;s++){
    if (s<17) prefetch(s0+s+1);
    #pragma unroll
    for (int nt=0;nt<8;nt++){
      short8 bf = *(short8*)&Bs[(nt*64+l)*8];
      acc[nt] = __builtin_amdgcn_mfma_f32_16x16x32_bf16(af, bf, acc[nt], 0,0,0);
    }
    __syncthreads();
    if (s<17){ combine(); __syncthreads(); }
  }
  #pragma unroll
  for (int nt=0;nt<8;nt++){
    int o = nt*16 + ln;
    float bias = half ? 0.f : dc_b[o];
    #pragma unroll
    for (int r=0;r<4;r++){
      int pxo = pbase + w*16 + q*4 + r;
      unsafeAtomicAdd(&dc_t[((size_t)b*HW + pxo)*NC + o], acc[nt][r] + bias);
    }
  }
}

// ---------------- K7: channel LayerNorm + sigmoid gate + multiply ----------------
__global__ __launch_bounds__(256) void epilogue(const float* __restrict__ dc_t,
    const float* __restrict__ dsc, const float* __restrict__ ln_g,
    const float* __restrict__ ln_b, float* __restrict__ out){
  __shared__ float T[64*129];
  __shared__ float Ps[4*64], Qs[4*64], Ms[64], Rs[64];
  int blk = blockIdx.x;
  int g = (blk>>3) + 72*(blk&7);             // match deform's region->XCD map
  int b = rfl(g/144); int pbase = rfl(g - (g/144)*144)*64;
  int t = threadIdx.x;
  #pragma unroll
  for (int i=0;i<8;i++){
    int idx = i*256 + t; int px = idx>>5, seg = idx&31;
    float4 v = *(const float4*)(dc_t + ((size_t)b*HW + pbase + px)*NC + seg*4);
    float* d = &T[px*129 + seg*4];
    d[0]=v.x; d[1]=v.y; d[2]=v.z; d[3]=v.w;
  }
  __syncthreads();
  int px = t&63, cg = t>>6;
  float s=0.f, ss=0.f;
  #pragma unroll
  for (int i=0;i<32;i++){ float v = T[px*129 + cg*32 + i]; s += v; ss = fmaf(v,v,ss); }
  Ps[cg*64+px] = s; Qs[cg*64+px] = ss;
  __syncthreads();
  if (t<64){
    float S = Ps[px]+Ps[64+px]+Ps[128+px]+Ps[192+px];
    float SS= Qs[px]+Qs[64+px]+Qs[128+px]+Qs[192+px];
    float m = S*(1.f/128.f);
    float var = SS*(1.f/128.f) - m*m;
    Ms[px] = m; Rs[px] = rsqrtf(var + 1e-5f);
  }
  __syncthreads();
  float m = Ms[px], rs = Rs[px];
  #pragma unroll 4
  for (int i=0;i<32;i++){
    int c = cg*32 + i;
    float ln = (T[px*129+c] - m)*rs*ln_g[c] + ln_b[c];
    float attn = 1.f/(1.f+__expf(-ln));
    size_t idx = (size_t)(b*NC+c)*HW + pbase + px;
    out[idx] = dsc[idx]*attn;
  }
}

extern "C" void kernel_launch(void* const* d_in, const int* in_sizes, int n_in,
                              void* d_out, int out_size, void* d_ws, size_t ws_size,
                              hipStream_t stream){
  const float* x    = (const float*)d_in[0];
  const float* dw_w = (const float*)d_in[1];
  const float* dw_b = (const float*)d_in[2];
  const float* pw_w = (const float*)d_in[3];
  const float* pw_b = (const float*)d_in[4];
  const float* off_w= (const float*)d_in[5];
  const float* off_b= (const float*)d_in[6];
  const float* dc_w = (const float*)d_in[7];
  const float* dc_b = (const float*)d_in[8];
  const float* ln_g = (const float*)d_in[9];
  const float* ln_b = (const float*)d_in[10];
  float* out = (float*)d_out;

  float* W    = (float*)d_ws;
  float*   bufA = W;                          // h1, then dsc (NCHW f32)
  float*   bufB = W + 4718592;                // h2, then dc_t (NHWC f32)
  u16*     dscT = (u16*)(W + 9437184);        // NHWC bf16 hi
  u16*     dscL = (u16*)(W + 11796480);       // NHWC bf16 lo residual
  float4*  wg   = (float4*)(W + 14155776);
  ushort4* ad   = (ushort4*)(W + 15482880);
  float*   st   = W + 16146432;
  u16*     wpwb = (u16*)(W + 16147456);
  u16*     wob  = (u16*)(W + 16155648);
  u16*     wdcb = (u16*)(W + 16174080);

  prep_weights<<<576, 256, 0, stream>>>(pw_w, off_w, dc_w, wpwb, wob, wdcb);
  dw_conv     <<<18432, 256, 0, stream>>>(x, dw_w, dw_b, bufA);
  pw_mfma     <<<576, 256, 0, stream>>>(bufA, wpwb, pw_b, bufB);
  inorm_stats <<<512, 256, 0, stream>>>(bufB, st);
  make_dsc    <<<1152, 256, 0, stream>>>(bufB, st, bufA, dscT, dscL);
  off_mfma    <<<576, 256, 0, stream>>>(dscT, dscL, wob, off_b, wg, ad);
  hipMemsetAsync(bufB, 0, (size_t)4718592*4, stream);   // zero dc_t for atomics
  deform_mfma <<<1152, 256, 0, stream>>>(dscT, wdcb, dc_b, wg, ad, bufB);
  epilogue    <<<576, 256, 0, stream>>>(bufB, bufA, ln_g, ln_b, out);
}

// Round 5
// 276.465 us; speedup vs baseline: 1.0619x; 1.0619x over previous
//
#include <hip/hip_runtime.h>
#include <hip/hip_fp16.h>
#include <math.h>

#define HW 9216
#define WD 96
#define NC 128

typedef unsigned short u16;
typedef _Float16 f16;
typedef __attribute__((ext_vector_type(8))) _Float16 half8;
typedef __attribute__((ext_vector_type(2))) _Float16 h2v;
typedef __attribute__((ext_vector_type(4))) float v4f;

__device__ __forceinline__ int rfl(int v){ return __builtin_amdgcn_readfirstlane(v); }
__device__ __forceinline__ u16 h2u(f16 h){ u16 u; __builtin_memcpy(&u,&h,2); return u; }
__device__ __forceinline__ h2v u2h2(unsigned u){ h2v h; __builtin_memcpy(&h,&u,4); return h; }

// ---------------- K0: weight prep (all fp16) ----------------
// wpwh[o][c]; wob[o][k*128+c] (pad to 32 rows); wdcf[o][k*128+c]
__global__ __launch_bounds__(256) void prep_weights(const float* __restrict__ pw_w,
    const float* __restrict__ off_w, const float* __restrict__ dc_w,
    f16* __restrict__ wpwh, f16* __restrict__ wob, f16* __restrict__ wdcf){
  int t = blockIdx.x*256 + threadIdx.x;
  if (t < 16384) wpwh[t] = (f16)pw_w[t];
  if (t < 36864){ int o = t/1152, r = t - o*1152; int k = r>>7, c = r&127;
                  wob[t] = (o<18) ? (f16)off_w[(o*128+c)*9+k] : (f16)0.f; }
  if (t < 147456){ int o = t/1152, r = t - o*1152; int k = r>>7, c = r&127;
                   wdcf[t] = (f16)dc_w[(o*128+c)*9 + k]; }
}

// ---------------- K1: depthwise 3x3 + bias (NCHW fp32) ----------------
__global__ __launch_bounds__(256) void dw_conv(const float* __restrict__ x,
    const float* __restrict__ w, const float* __restrict__ bias, float* __restrict__ h1){
  int n = blockIdx.x*256 + threadIdx.x;
  int bc = rfl(n / HW);
  int p = n - bc*HW;
  int c = bc & 127;
  int yy = p / WD, xx = p - (p/WD)*WD;
  const float* xc = x + (size_t)bc*HW;
  float acc = bias[c];
  #pragma unroll
  for (int r=0;r<3;r++){
    int y2 = yy + r - 1;
    #pragma unroll
    for (int cc2=0;cc2<3;cc2++){
      int x2 = xx + cc2 - 1;
      if (y2>=0 && y2<96 && x2>=0 && x2<96)
        acc = fmaf(w[c*9 + r*3 + cc2], xc[y2*WD + x2], acc);
    }
  }
  h1[n] = acc;
}

// ---------------- K2: pointwise 1x1 via MFMA (fp16) ----------------
__global__ __launch_bounds__(256) void pw_mfma(const float* __restrict__ h1,
    const f16* __restrict__ wpwh, const float* __restrict__ pw_b, float* __restrict__ h2){
  __shared__ f16 Aw[128*136];
  __shared__ f16 Bw[128*68];
  int blk = blockIdx.x; int row0 = blk*64;
  int b = rfl(row0/HW); int pbase = rfl(row0 - b*HW);
  int t = threadIdx.x;
  #pragma unroll
  for (int i=0;i<8;i++){
    int idx = i*256 + t; int o = idx>>4, seg = idx&15;
    *(half8*)&Aw[o*136 + seg*8] = *(const half8*)(wpwh + o*128 + seg*8);
  }
  #pragma unroll
  for (int i=0;i<8;i++){
    int idx = i*256 + t; int c = idx>>4, seg = idx&15;
    float4 v = *(const float4*)(h1 + (size_t)(b*NC+c)*HW + pbase + seg*4);
    ushort4 pk = make_ushort4(h2u((f16)v.x), h2u((f16)v.y), h2u((f16)v.z), h2u((f16)v.w));
    *(ushort4*)&Bw[c*68 + seg*4] = pk;
  }
  __syncthreads();
  int w = rfl(t>>6); int l = t&63; int q = l>>4; int ln = l&15;
  v4f acc[8];
  #pragma unroll
  for (int mt=0;mt<8;mt++) acc[mt] = (v4f){0.f,0.f,0.f,0.f};
  #pragma unroll
  for (int ks=0;ks<4;ks++){
    half8 bf;
    #pragma unroll
    for (int j=0;j<8;j++) bf[j] = Bw[(ks*32 + q*8 + j)*68 + w*16 + ln];
    #pragma unroll
    for (int mt=0;mt<8;mt++){
      half8 af = *(half8*)&Aw[(mt*16+ln)*136 + ks*32 + q*8];
      acc[mt] = __builtin_amdgcn_mfma_f32_16x16x32_f16(af, bf, acc[mt], 0,0,0);
    }
  }
  int px = pbase + w*16 + ln;
  #pragma unroll
  for (int mt=0;mt<8;mt++){
    #pragma unroll
    for (int r=0;r<4;r++){
      int o = mt*16 + q*4 + r;
      h2[(size_t)(b*NC+o)*HW + px] = acc[mt][r] + pw_b[o];
    }
  }
}

// ---------------- K3: InstanceNorm stats ----------------
__global__ __launch_bounds__(256) void inorm_stats(const float* __restrict__ h2, float* __restrict__ st){
  int bc = blockIdx.x;
  const float* src = h2 + (size_t)bc*HW;
  float s=0.f, ss=0.f;
  for (int i=threadIdx.x; i<HW; i+=256){ float v=src[i]; s+=v; ss=fmaf(v,v,ss); }
  #pragma unroll
  for (int off=32; off; off>>=1){ s += __shfl_down(s,off); ss += __shfl_down(ss,off); }
  __shared__ float rsm[2][4];
  int wave = threadIdx.x>>6, lane = threadIdx.x&63;
  if (lane==0){ rsm[0][wave]=s; rsm[1][wave]=ss; }
  __syncthreads();
  if (threadIdx.x==0){
    float S = rsm[0][0]+rsm[0][1]+rsm[0][2]+rsm[0][3];
    float SS= rsm[1][0]+rsm[1][1]+rsm[1][2]+rsm[1][3];
    float mu = S * (1.f/9216.f);
    float var = SS * (1.f/9216.f) - mu*mu;
    st[bc*2]   = mu;
    st[bc*2+1] = rsqrtf(var + 1e-5f);
  }
}

// ---------------- K4: dsc (NCHW fp32) + dscT/dscL (NHWC fp16 hi/lo) ----------------
__global__ __launch_bounds__(256) void make_dsc(const float* __restrict__ h2,
    const float* __restrict__ st, float* __restrict__ dsc,
    f16* __restrict__ dscT, f16* __restrict__ dscL){
  int blk = blockIdx.x;
  int pt = blk % 144; int r = blk/144; int ch = r & 1; int b = r >> 1;
  int c0 = ch*64, pbase = pt*64;
  __shared__ float tile[64][65];
  int tr = threadIdx.x >> 2;
  int g  = threadIdx.x & 3;
  int c  = c0 + tr;
  float mu = st[(b*128+c)*2];
  float rs = st[(b*128+c)*2+1];
  const float* src = h2 + (size_t)(b*128+c)*HW + pbase + g*16;
  float* d = dsc + (size_t)(b*128+c)*HW + pbase + g*16;
  #pragma unroll
  for (int i=0;i<4;i++){
    float4 v = *(const float4*)(src + i*4);
    v.x=(v.x-mu)*rs; v.y=(v.y-mu)*rs; v.z=(v.z-mu)*rs; v.w=(v.w-mu)*rs;
    *(float4*)(d + i*4) = v;
    tile[tr][g*16+i*4+0]=v.x; tile[tr][g*16+i*4+1]=v.y;
    tile[tr][g*16+i*4+2]=v.z; tile[tr][g*16+i*4+3]=v.w;
  }
  __syncthreads();
  int pr = tr;
  f16* dt = dscT + ((size_t)b*HW + pbase + pr)*NC + c0 + g*16;
  f16* dl = dscL + ((size_t)b*HW + pbase + pr)*NC + c0 + g*16;
  #pragma unroll
  for (int i=0;i<4;i++){
    float v0 = tile[g*16+i*4+0][pr], v1 = tile[g*16+i*4+1][pr];
    float v2 = tile[g*16+i*4+2][pr], v3 = tile[g*16+i*4+3][pr];
    f16 h0=(f16)v0, h1=(f16)v1, h2_=(f16)v2, h3=(f16)v3;
    f16 l0=(f16)(v0-(float)h0), l1=(f16)(v1-(float)h1);
    f16 l2=(f16)(v2-(float)h2_), l3=(f16)(v3-(float)h3);
    *(ushort4*)(dt + i*4) = make_ushort4(h2u(h0),h2u(h1),h2u(h2_),h2u(h3));
    *(ushort4*)(dl + i*4) = make_ushort4(h2u(l0),h2u(l1),h2u(l2),h2u(l3));
  }
}

// ---------------- K5: offset conv via MFMA (fp16 hi/lo, 1 barrier/step) + bilinear precomp ----
__global__ __launch_bounds__(256) void off_mfma(const f16* __restrict__ dscT,
    const f16* __restrict__ dscL, const f16* __restrict__ wob,
    const float* __restrict__ off_b, float4* __restrict__ wg, ushort4* __restrict__ ad){
  __shared__ f16 Bs[2][2048];
  __shared__ float Po[18*64];
  int blk = blockIdx.x;
  int g = (blk>>3) + 72*(blk&7);             // XCD swizzle
  int b = rfl(g/144); int pbase = rfl(g - (g/144)*144)*64;
  int t = threadIdx.x;
  int l = t&63; int w = rfl(t>>6);
  int ln = l&15, q = l>>4;
  int P = pbase + w*16 + ln;
  int py = P/96, pxx = P - 96*(P/96);
  int ob = (t&15) + ((t>>6)&1)*16;           // B staging o-row
  int subB = t>>7, qB = (t>>4)&3;
  const f16* hib = dscT + (size_t)b*HW*NC;
  const f16* lob = dscL + (size_t)b*HW*NC;
  uint4 nh0,nh1,nl0,nl1, nwb;
  const uint4 Z = (uint4){0,0,0,0};
  auto prefetch = [&](int s){
    int tap = s>>1; int cb = (s&1)*64;
    int y2 = py + tap/3 - 1, x2 = pxx + tap%3 - 1;
    bool valid = ((unsigned)y2 < 96u) && ((unsigned)x2 < 96u);
    int off = (y2*96 + x2)*NC + cb + q*8;
    nh0 = valid ? *(const uint4*)(hib + off)      : Z;
    nh1 = valid ? *(const uint4*)(hib + off + 32) : Z;
    nl0 = valid ? *(const uint4*)(lob + off)      : Z;
    nl1 = valid ? *(const uint4*)(lob + off + 32) : Z;
    nwb = *(const uint4*)(wob + ob*1152 + tap*128 + cb + subB*32 + qB*8);
  };
  uint4 ch0,ch1,cl0,cl1;
  v4f acc[2];
  acc[0] = (v4f){0.f,0.f,0.f,0.f}; acc[1] = (v4f){0.f,0.f,0.f,0.f};
  prefetch(0);
  ch0=nh0; ch1=nh1; cl0=nl0; cl1=nl1;
  *(uint4*)&Bs[0][t*8] = nwb;
  __syncthreads();
  #pragma unroll 2
  for (int s=0;s<18;s++){
    if (s<17) prefetch(s+1);
    f16* B = Bs[s&1];
    half8 b00 = *(half8*)&B[(0*64+l)*8];
    half8 b01 = *(half8*)&B[(1*64+l)*8];
    half8 b10 = *(half8*)&B[(2*64+l)*8];
    half8 b11 = *(half8*)&B[(3*64+l)*8];
    half8 a0,a1,a2,a3;
    __builtin_memcpy(&a0,&ch0,16); __builtin_memcpy(&a1,&ch1,16);
    __builtin_memcpy(&a2,&cl0,16); __builtin_memcpy(&a3,&cl1,16);
    acc[0] = __builtin_amdgcn_mfma_f32_16x16x32_f16(a0, b00, acc[0], 0,0,0);
    acc[1] = __builtin_amdgcn_mfma_f32_16x16x32_f16(a0, b01, acc[1], 0,0,0);
    acc[0] = __builtin_amdgcn_mfma_f32_16x16x32_f16(a2, b00, acc[0], 0,0,0);
    acc[1] = __builtin_amdgcn_mfma_f32_16x16x32_f16(a2, b01, acc[1], 0,0,0);
    acc[0] = __builtin_amdgcn_mfma_f32_16x16x32_f16(a1, b10, acc[0], 0,0,0);
    acc[1] = __builtin_amdgcn_mfma_f32_16x16x32_f16(a1, b11, acc[1], 0,0,0);
    acc[0] = __builtin_amdgcn_mfma_f32_16x16x32_f16(a3, b10, acc[0], 0,0,0);
    acc[1] = __builtin_amdgcn_mfma_f32_16x16x32_f16(a3, b11, acc[1], 0,0,0);
    if (s<17){
      ch0=nh0; ch1=nh1; cl0=nl0; cl1=nl1;
      *(uint4*)&Bs[(s+1)&1][t*8] = nwb;
    }
    __syncthreads();
  }
  #pragma unroll
  for (int nt=0;nt<2;nt++){
    int o = nt*16 + ln;
    if (o < 18){
      float obias = off_b[o];
      #pragma unroll
      for (int r=0;r<4;r++) Po[o*64 + w*16 + q*4 + r] = acc[nt][r] + obias;
    }
  }
  __syncthreads();
  #pragma unroll
  for (int i=0;i<3;i++){
    int idx = i*256 + t;
    if (idx < 576){
      int pxl = idx & 63, k = idx >> 6;
      int Pp = pbase + pxl;
      float dy = Po[(2*k)*64 + pxl], dx = Po[(2*k+1)*64 + pxl];
      float ys = (float)(Pp/96 + k/3 - 1) + dy;
      float xs = (float)(Pp%96 + k%3 - 1) + dx;
      float fy0 = floorf(ys), fx0 = floorf(xs);
      float wy = ys - fy0, wx = xs - fx0;
      int y0 = (int)fy0, x0 = (int)fx0;
      int y1 = y0+1, x1 = x0+1;
      float vy0 = (y0>=0 && y0<=95) ? 1.f : 0.f;
      float vy1 = (y1>=0 && y1<=95) ? 1.f : 0.f;
      float vx0 = (x0>=0 && x0<=95) ? 1.f : 0.f;
      float vx1 = (x1>=0 && x1<=95) ? 1.f : 0.f;
      int y0c=min(max(y0,0),95), y1c=min(max(y1,0),95);
      int x0c=min(max(x0,0),95), x1c=min(max(x1,0),95);
      float4 w4;
      w4.x = (1.f-wy)*(1.f-wx)*vy0*vx0;
      w4.y = (1.f-wy)*wx*vy0*vx1;
      w4.z = wy*(1.f-wx)*vy1*vx0;
      w4.w = wy*wx*vy1*vx1;
      int gi = (b*9 + k)*HW + pbase + pxl;
      wg[gi] = w4;
      ad[gi] = make_ushort4((u16)(y0c*WD+x0c), (u16)(y0c*WD+x1c),
                            (u16)(y1c*WD+x0c), (u16)(y1c*WD+x1c));
    }
  }
}

// ---------------- K6: deform conv (register gather + pk_fma combine, K=64 steps, 1 barrier) ----
// Block: 64 px x 128 o. Wave w: m-tile w (gather duty) AND o-slice w*32..w*32+32 (compute duty).
__global__ __launch_bounds__(256) void deform_mfma(const f16* __restrict__ dscT,
    const f16* __restrict__ wdcf, const float* __restrict__ dc_b,
    const float4* __restrict__ wg, const ushort4* __restrict__ ad,
    float* __restrict__ dc_t){
  __shared__ f16 As[2][2][2048];             // [buf][c2][(mt*64+l)*8]
  int blk = blockIdx.x;                      // 576
  int g = (blk>>3) + 72*(blk&7);             // XCD swizzle
  int b = rfl(g/144); int pbase = rfl(g - (g/144)*144)*64;
  int t = threadIdx.x;
  int l = t&63; int w = rfl(t>>6);
  int ln = l&15, q = l>>4;
  int o_lo = w*32 + ln;                      // weight rows (nt0; +16 for nt1)
  const f16* db0 = dscT + (size_t)b*HW*NC;
  int gibase = b*9*HW + pbase + w*16 + ln;   // wg/ad index for tap k: gibase + k*HW
  float4 wv, wvn; ushort4 av, avn;
  h2v wx2, wy2, wz2, ww2;
  uint4 Gn[2][4];                            // [c2][corner] gathers for next step
  uint4 WBn[2][2], WBc[2][2];                // [c2][nt] weight frags
  auto cvtw = [&](){
    f16 hx=(f16)wv.x, hy=(f16)wv.y, hz=(f16)wv.z, hw=(f16)wv.w;
    wx2=(h2v){hx,hx}; wy2=(h2v){hy,hy}; wz2=(h2v){hz,hz}; ww2=(h2v){hw,hw};
  };
  auto gather = [&](int s){
    const f16* d0 = db0 + (s&1)*64 + q*8;
    const f16* p0 = d0 + (int)av.x*NC;
    const f16* p1 = d0 + (int)av.y*NC;
    const f16* p2 = d0 + (int)av.z*NC;
    const f16* p3 = d0 + (int)av.w*NC;
    Gn[0][0]=*(const uint4*)p0;      Gn[0][1]=*(const uint4*)p1;
    Gn[0][2]=*(const uint4*)p2;      Gn[0][3]=*(const uint4*)p3;
    Gn[1][0]=*(const uint4*)(p0+32); Gn[1][1]=*(const uint4*)(p1+32);
    Gn[1][2]=*(const uint4*)(p2+32); Gn[1][3]=*(const uint4*)(p3+32);
  };
  auto wload = [&](int s){
    const f16* wp = wdcf + (s>>1)*128 + (s&1)*64 + q*8;
    WBn[0][0] = *(const uint4*)(wp + (size_t)o_lo*1152);
    WBn[1][0] = *(const uint4*)(wp + (size_t)o_lo*1152 + 32);
    WBn[0][1] = *(const uint4*)(wp + (size_t)(o_lo+16)*1152);
    WBn[1][1] = *(const uint4*)(wp + (size_t)(o_lo+16)*1152 + 32);
  };
  auto commitA = [&](int buf){
    #pragma unroll
    for (int c2=0;c2<2;c2++){
      unsigned ga[4], gb[4], gc[4], gd[4], ou[4];
      __builtin_memcpy(ga,&Gn[c2][0],16); __builtin_memcpy(gb,&Gn[c2][1],16);
      __builtin_memcpy(gc,&Gn[c2][2],16); __builtin_memcpy(gd,&Gn[c2][3],16);
      #pragma unroll
      for (int j=0;j<4;j++){
        h2v r = u2h2(ga[j])*wx2;
        r += u2h2(gb[j])*wy2;
        r += u2h2(gc[j])*wz2;
        r += u2h2(gd[j])*ww2;
        unsigned uu; __builtin_memcpy(&uu,&r,4); ou[j]=uu;
      }
      uint4 pk; __builtin_memcpy(&pk,ou,16);
      *(uint4*)&As[buf][c2][(w*64+l)*8] = pk;
    }
  };
  v4f acc[4][2];
  #pragma unroll
  for (int mt=0;mt<4;mt++){ acc[mt][0]=(v4f){0,0,0,0}; acc[mt][1]=(v4f){0,0,0,0}; }
  // prologue: tap0 coords, tap1 lookahead, step0 gathers+weights
  wv = wg[gibase]; av = ad[gibase];
  wvn = wg[gibase + HW]; avn = ad[gibase + HW];
  cvtw();
  gather(0); wload(0);
  #pragma unroll
  for (int c2=0;c2<2;c2++){ WBc[c2][0]=WBn[c2][0]; WBc[c2][1]=WBn[c2][1]; }
  commitA(0);
  __syncthreads();
  #pragma unroll 2
  for (int s=0;s<18;s++){
    if (s<17){
      if (((s+1)&1)==0){                     // s+1 starts a new tap
        wv=wvn; av=avn; cvtw();
        int tapn = (s+1)>>1;
        if (tapn < 8){ wvn = wg[gibase + (tapn+1)*HW]; avn = ad[gibase + (tapn+1)*HW]; }
      }
      gather(s+1); wload(s+1);
    }
    int cur = s&1;
    #pragma unroll
    for (int c2=0;c2<2;c2++){
      half8 bw0, bw1;
      __builtin_memcpy(&bw0,&WBc[c2][0],16); __builtin_memcpy(&bw1,&WBc[c2][1],16);
      #pragma unroll
      for (int mt=0;mt<4;mt++){
        half8 af = *(half8*)&As[cur][c2][(mt*64+l)*8];
        acc[mt][0] = __builtin_amdgcn_mfma_f32_16x16x32_f16(af, bw0, acc[mt][0], 0,0,0);
        acc[mt][1] = __builtin_amdgcn_mfma_f32_16x16x32_f16(af, bw1, acc[mt][1], 0,0,0);
      }
    }
    if (s<17){
      commitA((s+1)&1);
      #pragma unroll
      for (int c2=0;c2<2;c2++){ WBc[c2][0]=WBn[c2][0]; WBc[c2][1]=WBn[c2][1]; }
    }
    __syncthreads();
  }
  float bias0 = dc_b[w*32 + ln], bias1 = dc_b[w*32 + 16 + ln];
  #pragma unroll
  for (int mt=0;mt<4;mt++){
    #pragma unroll
    for (int r=0;r<4;r++){
      int pix = pbase + mt*16 + q*4 + r;
      float* dst = dc_t + ((size_t)b*HW + pix)*NC + w*32 + ln;
      dst[0]  = acc[mt][0][r] + bias0;
      dst[16] = acc[mt][1][r] + bias1;
    }
  }
}

// ---------------- K7: channel LayerNorm + sigmoid gate + multiply ----------------
__global__ __launch_bounds__(256) void epilogue(const float* __restrict__ dc_t,
    const float* __restrict__ dsc, const float* __restrict__ ln_g,
    const float* __restrict__ ln_b, float* __restrict__ out){
  __shared__ float T[64*129];
  __shared__ float Ps[4*64], Qs[4*64], Ms[64], Rs[64];
  int blk = blockIdx.x;
  int g = (blk>>3) + 72*(blk&7);
  int b = rfl(g/144); int pbase = rfl(g - (g/144)*144)*64;
  int t = threadIdx.x;
  #pragma unroll
  for (int i=0;i<8;i++){
    int idx = i*256 + t; int px = idx>>5, seg = idx&31;
    float4 v = *(const float4*)(dc_t + ((size_t)b*HW + pbase + px)*NC + seg*4);
    float* d = &T[px*129 + seg*4];
    d[0]=v.x; d[1]=v.y; d[2]=v.z; d[3]=v.w;
  }
  __syncthreads();
  int px = t&63, cg = t>>6;
  float s=0.f, ss=0.f;
  #pragma unroll
  for (int i=0;i<32;i++){ float v = T[px*129 + cg*32 + i]; s += v; ss = fmaf(v,v,ss); }
  Ps[cg*64+px] = s; Qs[cg*64+px] = ss;
  __syncthreads();
  if (t<64){
    float S = Ps[px]+Ps[64+px]+Ps[128+px]+Ps[192+px];
    float SS= Qs[px]+Qs[64+px]+Qs[128+px]+Qs[192+px];
    float m = S*(1.f/128.f);
    float var = SS*(1.f/128.f) - m*m;
    Ms[px] = m; Rs[px] = rsqrtf(var + 1e-5f);
  }
  __syncthreads();
  float m = Ms[px], rs = Rs[px];
  #pragma unroll 4
  for (int i=0;i<32;i++){
    int c = cg*32 + i;
    float ln = (T[px*129+c] - m)*rs*ln_g[c] + ln_b[c];
    float attn = 1.f/(1.f+__expf(-ln));
    size_t idx = (size_t)(b*NC+c)*HW + pbase + px;
    out[idx] = dsc[idx]*attn;
  }
}

extern "C" void kernel_launch(void* const* d_in, const int* in_sizes, int n_in,
                              void* d_out, int out_size, void* d_ws, size_t ws_size,
                              hipStream_t stream){
  const float* x    = (const float*)d_in[0];
  const float* dw_w = (const float*)d_in[1];
  const float* dw_b = (const float*)d_in[2];
  const float* pw_w = (const float*)d_in[3];
  const float* pw_b = (const float*)d_in[4];
  const float* off_w= (const float*)d_in[5];
  const float* off_b= (const float*)d_in[6];
  const float* dc_w = (const float*)d_in[7];
  const float* dc_b = (const float*)d_in[8];
  const float* ln_g = (const float*)d_in[9];
  const float* ln_b = (const float*)d_in[10];
  float* out = (float*)d_out;

  float* W    = (float*)d_ws;
  float*   bufA = W;                          // h1, then dsc (NCHW f32)
  float*   bufB = W + 4718592;                // h2, then dc_t (NHWC f32)
  f16*     dscT = (f16*)(W + 9437184);        // NHWC fp16 hi
  f16*     dscL = (f16*)(W + 11796480);       // NHWC fp16 lo residual
  float4*  wg   = (float4*)(W + 14155776);
  ushort4* ad   = (ushort4*)(W + 15482880);
  float*   st   = W + 16146432;
  f16*     wpwh = (f16*)(W + 16147456);
  f16*     wob  = (f16*)(W + 16155648);
  f16*     wdcf = (f16*)(W + 16174080);

  prep_weights<<<576, 256, 0, stream>>>(pw_w, off_w, dc_w, wpwh, wob, wdcf);
  dw_conv     <<<18432, 256, 0, stream>>>(x, dw_w, dw_b, bufA);
  pw_mfma     <<<576, 256, 0, stream>>>(bufA, wpwh, pw_b, bufB);
  inorm_stats <<<512, 256, 0, stream>>>(bufB, st);
  make_dsc    <<<1152, 256, 0, stream>>>(bufB, st, bufA, dscT, dscL);
  off_mfma    <<<576, 256, 0, stream>>>(dscT, dscL, wob, off_b, wg, ad);
  deform_mfma <<<576, 256, 0, stream>>>(dscT, wdcf, dc_b, wg, ad, bufB);
  epilogue    <<<576, 256, 0, stream>>>(bufB, bufA, ln_g, ln_b, out);
}

// Round 6
// 254.249 us; speedup vs baseline: 1.1547x; 1.0874x over previous
//
#include <hip/hip_runtime.h>
#include <hip/hip_fp16.h>
#include <math.h>

#define HW 9216
#define WD 96
#define NC 128

typedef unsigned short u16;
typedef _Float16 f16;
typedef __attribute__((ext_vector_type(8))) _Float16 half8;
typedef __attribute__((ext_vector_type(2))) _Float16 h2v;
typedef __attribute__((ext_vector_type(4))) float v4f;

__device__ __forceinline__ int rfl(int v){ return __builtin_amdgcn_readfirstlane(v); }
__device__ __forceinline__ u16 h2u(f16 h){ u16 u; __builtin_memcpy(&u,&h,2); return u; }
__device__ __forceinline__ h2v u2h2(unsigned u){ h2v h; __builtin_memcpy(&h,&u,4); return h; }

// ---------------- K0: weight prep (all fp16) ----------------
// wpwh[o][c]; wob[o][k*128+c] (pad to 32 rows);
// wfr: deform weights in MFMA-fragment-linear order:
//   idx = (((s*2+c2)*8 + o>>4)*64 + q*16 + (o&15))*8 + j   (s=K64-step, k_in_32 = q*8+j)
__global__ __launch_bounds__(256) void prep_weights(const float* __restrict__ pw_w,
    const float* __restrict__ off_w, const float* __restrict__ dc_w,
    f16* __restrict__ wpwh, f16* __restrict__ wob, f16* __restrict__ wfr){
  int t = blockIdx.x*256 + threadIdx.x;
  if (t < 16384) wpwh[t] = (f16)pw_w[t];
  if (t < 36864){ int o = t/1152, r = t - o*1152; int k = r>>7, c = r&127;
                  wob[t] = (o<18) ? (f16)off_w[(o*128+c)*9+k] : (f16)0.f; }
  if (t < 147456){
    int o = t/1152, k_lin = t - o*1152;
    int tap = k_lin>>7, c = k_lin&127;
    int s = k_lin>>6, c2 = (k_lin>>5)&1, qw = (k_lin>>3)&3, j = k_lin&7;
    int idx = (((s*2 + c2)*8 + (o>>4))*64 + qw*16 + (o&15))*8 + j;
    wfr[idx] = (f16)dc_w[(o*128+c)*9 + tap];
  }
}

// ---------------- K1: depthwise 3x3 + bias (NCHW fp32) ----------------
__global__ __launch_bounds__(256) void dw_conv(const float* __restrict__ x,
    const float* __restrict__ w, const float* __restrict__ bias, float* __restrict__ h1){
  int n = blockIdx.x*256 + threadIdx.x;
  int bc = rfl(n / HW);
  int p = n - bc*HW;
  int c = bc & 127;
  int yy = p / WD, xx = p - (p/WD)*WD;
  const float* xc = x + (size_t)bc*HW;
  float acc = bias[c];
  #pragma unroll
  for (int r=0;r<3;r++){
    int y2 = yy + r - 1;
    #pragma unroll
    for (int cc2=0;cc2<3;cc2++){
      int x2 = xx + cc2 - 1;
      if (y2>=0 && y2<96 && x2>=0 && x2<96)
        acc = fmaf(w[c*9 + r*3 + cc2], xc[y2*WD + x2], acc);
    }
  }
  h1[n] = acc;
}

// ---------------- K2: pointwise 1x1 via MFMA (fp16) ----------------
__global__ __launch_bounds__(256) void pw_mfma(const float* __restrict__ h1,
    const f16* __restrict__ wpwh, const float* __restrict__ pw_b, float* __restrict__ h2){
  __shared__ f16 Aw[128*136];
  __shared__ f16 Bw[128*68];
  int blk = blockIdx.x; int row0 = blk*64;
  int b = rfl(row0/HW); int pbase = rfl(row0 - b*HW);
  int t = threadIdx.x;
  #pragma unroll
  for (int i=0;i<8;i++){
    int idx = i*256 + t; int o = idx>>4, seg = idx&15;
    *(half8*)&Aw[o*136 + seg*8] = *(const half8*)(wpwh + o*128 + seg*8);
  }
  #pragma unroll
  for (int i=0;i<8;i++){
    int idx = i*256 + t; int c = idx>>4, seg = idx&15;
    float4 v = *(const float4*)(h1 + (size_t)(b*NC+c)*HW + pbase + seg*4);
    ushort4 pk = make_ushort4(h2u((f16)v.x), h2u((f16)v.y), h2u((f16)v.z), h2u((f16)v.w));
    *(ushort4*)&Bw[c*68 + seg*4] = pk;
  }
  __syncthreads();
  int w = rfl(t>>6); int l = t&63; int q = l>>4; int ln = l&15;
  v4f acc[8];
  #pragma unroll
  for (int mt=0;mt<8;mt++) acc[mt] = (v4f){0.f,0.f,0.f,0.f};
  #pragma unroll
  for (int ks=0;ks<4;ks++){
    half8 bf;
    #pragma unroll
    for (int j=0;j<8;j++) bf[j] = Bw[(ks*32 + q*8 + j)*68 + w*16 + ln];
    #pragma unroll
    for (int mt=0;mt<8;mt++){
      half8 af = *(half8*)&Aw[(mt*16+ln)*136 + ks*32 + q*8];
      acc[mt] = __builtin_amdgcn_mfma_f32_16x16x32_f16(af, bf, acc[mt], 0,0,0);
    }
  }
  int px = pbase + w*16 + ln;
  #pragma unroll
  for (int mt=0;mt<8;mt++){
    #pragma unroll
    for (int r=0;r<4;r++){
      int o = mt*16 + q*4 + r;
      h2[(size_t)(b*NC+o)*HW + px] = acc[mt][r] + pw_b[o];
    }
  }
}

// ---------------- K3: InstanceNorm stats ----------------
__global__ __launch_bounds__(256) void inorm_stats(const float* __restrict__ h2, float* __restrict__ st){
  int bc = blockIdx.x;
  const float* src = h2 + (size_t)bc*HW;
  float s=0.f, ss=0.f;
  for (int i=threadIdx.x; i<HW; i+=256){ float v=src[i]; s+=v; ss=fmaf(v,v,ss); }
  #pragma unroll
  for (int off=32; off; off>>=1){ s += __shfl_down(s,off); ss += __shfl_down(ss,off); }
  __shared__ float rsm[2][4];
  int wave = threadIdx.x>>6, lane = threadIdx.x&63;
  if (lane==0){ rsm[0][wave]=s; rsm[1][wave]=ss; }
  __syncthreads();
  if (threadIdx.x==0){
    float S = rsm[0][0]+rsm[0][1]+rsm[0][2]+rsm[0][3];
    float SS= rsm[1][0]+rsm[1][1]+rsm[1][2]+rsm[1][3];
    float mu = S * (1.f/9216.f);
    float var = SS * (1.f/9216.f) - mu*mu;
    st[bc*2]   = mu;
    st[bc*2+1] = rsqrtf(var + 1e-5f);
  }
}

// ---------------- K4: dsc (NCHW fp32) + dscT/dscL (NHWC fp16 hi/lo) ----------------
__global__ __launch_bounds__(256) void make_dsc(const float* __restrict__ h2,
    const float* __restrict__ st, float* __restrict__ dsc,
    f16* __restrict__ dscT, f16* __restrict__ dscL){
  int blk = blockIdx.x;
  int pt = blk % 144; int r = blk/144; int ch = r & 1; int b = r >> 1;
  int c0 = ch*64, pbase = pt*64;
  __shared__ float tile[64][65];
  int tr = threadIdx.x >> 2;
  int g  = threadIdx.x & 3;
  int c  = c0 + tr;
  float mu = st[(b*128+c)*2];
  float rs = st[(b*128+c)*2+1];
  const float* src = h2 + (size_t)(b*128+c)*HW + pbase + g*16;
  float* d = dsc + (size_t)(b*128+c)*HW + pbase + g*16;
  #pragma unroll
  for (int i=0;i<4;i++){
    float4 v = *(const float4*)(src + i*4);
    v.x=(v.x-mu)*rs; v.y=(v.y-mu)*rs; v.z=(v.z-mu)*rs; v.w=(v.w-mu)*rs;
    *(float4*)(d + i*4) = v;
    tile[tr][g*16+i*4+0]=v.x; tile[tr][g*16+i*4+1]=v.y;
    tile[tr][g*16+i*4+2]=v.z; tile[tr][g*16+i*4+3]=v.w;
  }
  __syncthreads();
  int pr = tr;
  f16* dt = dscT + ((size_t)b*HW + pbase + pr)*NC + c0 + g*16;
  f16* dl = dscL + ((size_t)b*HW + pbase + pr)*NC + c0 + g*16;
  #pragma unroll
  for (int i=0;i<4;i++){
    float v0 = tile[g*16+i*4+0][pr], v1 = tile[g*16+i*4+1][pr];
    float v2 = tile[g*16+i*4+2][pr], v3 = tile[g*16+i*4+3][pr];
    f16 h0=(f16)v0, h1=(f16)v1, h2_=(f16)v2, h3=(f16)v3;
    f16 l0=(f16)(v0-(float)h0), l1=(f16)(v1-(float)h1);
    f16 l2=(f16)(v2-(float)h2_), l3=(f16)(v3-(float)h3);
    *(ushort4*)(dt + i*4) = make_ushort4(h2u(h0),h2u(h1),h2u(h2_),h2u(h3));
    *(ushort4*)(dl + i*4) = make_ushort4(h2u(l0),h2u(l1),h2u(l2),h2u(l3));
  }
}

// ---------------- K5: offset conv via MFMA (fp16 hi/lo, 1 barrier/step) + bilinear precomp ----
__global__ __launch_bounds__(256) void off_mfma(const f16* __restrict__ dscT,
    const f16* __restrict__ dscL, const f16* __restrict__ wob,
    const float* __restrict__ off_b, float4* __restrict__ wg, ushort4* __restrict__ ad){
  __shared__ f16 Bs[2][2048];
  __shared__ float Po[18*64];
  int blk = blockIdx.x;
  int g = (blk>>3) + 72*(blk&7);             // XCD swizzle
  int b = rfl(g/144); int pbase = rfl(g - (g/144)*144)*64;
  int t = threadIdx.x;
  int l = t&63; int w = rfl(t>>6);
  int ln = l&15, q = l>>4;
  int P = pbase + w*16 + ln;
  int py = P/96, pxx = P - 96*(P/96);
  int ob = (t&15) + ((t>>6)&1)*16;           // B staging o-row
  int subB = t>>7, qB = (t>>4)&3;
  const f16* hib = dscT + (size_t)b*HW*NC;
  const f16* lob = dscL + (size_t)b*HW*NC;
  uint4 nh0,nh1,nl0,nl1, nwb;
  const uint4 Z = (uint4){0,0,0,0};
  auto prefetch = [&](int s){
    int tap = s>>1; int cb = (s&1)*64;
    int y2 = py + tap/3 - 1, x2 = pxx + tap%3 - 1;
    bool valid = ((unsigned)y2 < 96u) && ((unsigned)x2 < 96u);
    int off = (y2*96 + x2)*NC + cb + q*8;
    nh0 = valid ? *(const uint4*)(hib + off)      : Z;
    nh1 = valid ? *(const uint4*)(hib + off + 32) : Z;
    nl0 = valid ? *(const uint4*)(lob + off)      : Z;
    nl1 = valid ? *(const uint4*)(lob + off + 32) : Z;
    nwb = *(const uint4*)(wob + ob*1152 + tap*128 + cb + subB*32 + qB*8);
  };
  uint4 ch0,ch1,cl0,cl1;
  v4f acc[2];
  acc[0] = (v4f){0.f,0.f,0.f,0.f}; acc[1] = (v4f){0.f,0.f,0.f,0.f};
  prefetch(0);
  ch0=nh0; ch1=nh1; cl0=nl0; cl1=nl1;
  *(uint4*)&Bs[0][t*8] = nwb;
  __syncthreads();
  #pragma unroll 2
  for (int s=0;s<18;s++){
    if (s<17) prefetch(s+1);
    f16* B = Bs[s&1];
    half8 b00 = *(half8*)&B[(0*64+l)*8];
    half8 b01 = *(half8*)&B[(1*64+l)*8];
    half8 b10 = *(half8*)&B[(2*64+l)*8];
    half8 b11 = *(half8*)&B[(3*64+l)*8];
    half8 a0,a1,a2,a3;
    __builtin_memcpy(&a0,&ch0,16); __builtin_memcpy(&a1,&ch1,16);
    __builtin_memcpy(&a2,&cl0,16); __builtin_memcpy(&a3,&cl1,16);
    acc[0] = __builtin_amdgcn_mfma_f32_16x16x32_f16(a0, b00, acc[0], 0,0,0);
    acc[1] = __builtin_amdgcn_mfma_f32_16x16x32_f16(a0, b01, acc[1], 0,0,0);
    acc[0] = __builtin_amdgcn_mfma_f32_16x16x32_f16(a2, b00, acc[0], 0,0,0);
    acc[1] = __builtin_amdgcn_mfma_f32_16x16x32_f16(a2, b01, acc[1], 0,0,0);
    acc[0] = __builtin_amdgcn_mfma_f32_16x16x32_f16(a1, b10, acc[0], 0,0,0);
    acc[1] = __builtin_amdgcn_mfma_f32_16x16x32_f16(a1, b11, acc[1], 0,0,0);
    acc[0] = __builtin_amdgcn_mfma_f32_16x16x32_f16(a3, b10, acc[0], 0,0,0);
    acc[1] = __builtin_amdgcn_mfma_f32_16x16x32_f16(a3, b11, acc[1], 0,0,0);
    if (s<17){
      ch0=nh0; ch1=nh1; cl0=nl0; cl1=nl1;
      *(uint4*)&Bs[(s+1)&1][t*8] = nwb;
    }
    __syncthreads();
  }
  #pragma unroll
  for (int nt=0;nt<2;nt++){
    int o = nt*16 + ln;
    if (o < 18){
      float obias = off_b[o];
      #pragma unroll
      for (int r=0;r<4;r++) Po[o*64 + w*16 + q*4 + r] = acc[nt][r] + obias;
    }
  }
  __syncthreads();
  #pragma unroll
  for (int i=0;i<3;i++){
    int idx = i*256 + t;
    if (idx < 576){
      int pxl = idx & 63, k = idx >> 6;
      int Pp = pbase + pxl;
      float dy = Po[(2*k)*64 + pxl], dx = Po[(2*k+1)*64 + pxl];
      float ys = (float)(Pp/96 + k/3 - 1) + dy;
      float xs = (float)(Pp%96 + k%3 - 1) + dx;
      float fy0 = floorf(ys), fx0 = floorf(xs);
      float wy = ys - fy0, wx = xs - fx0;
      int y0 = (int)fy0, x0 = (int)fx0;
      int y1 = y0+1, x1 = x0+1;
      float vy0 = (y0>=0 && y0<=95) ? 1.f : 0.f;
      float vy1 = (y1>=0 && y1<=95) ? 1.f : 0.f;
      float vx0 = (x0>=0 && x0<=95) ? 1.f : 0.f;
      float vx1 = (x1>=0 && x1<=95) ? 1.f : 0.f;
      int y0c=min(max(y0,0),95), y1c=min(max(y1,0),95);
      int x0c=min(max(x0,0),95), x1c=min(max(x1,0),95);
      float4 w4;
      w4.x = (1.f-wy)*(1.f-wx)*vy0*vx0;
      w4.y = (1.f-wy)*wx*vy0*vx1;
      w4.z = wy*(1.f-wx)*vy1*vx0;
      w4.w = wy*wx*vy1*vx1;
      int gi = (b*9 + k)*HW + pbase + pxl;
      wg[gi] = w4;
      ad[gi] = make_ushort4((u16)(y0c*WD+x0c), (u16)(y0c*WD+x1c),
                            (u16)(y1c*WD+x0c), (u16)(y1c*WD+x1c));
    }
  }
}

// ---------------- K6: deform conv, depth-2 pipeline, 32px x 128o blocks ----------------
// Wave w: gathers (px-group w>>1, c2-half w&1); computes o-slice [w*32, w*32+32).
__global__ __launch_bounds__(256) void deform_mfma(const f16* __restrict__ dscT,
    const f16* __restrict__ wfr, const float* __restrict__ dc_b,
    const float4* __restrict__ wg, const ushort4* __restrict__ ad,
    float* __restrict__ dc_t){
  __shared__ f16 As[2][2][1024];             // [buf][c2][(mt*64+l)*8]
  int blk = blockIdx.x;                      // 1152
  int g = (blk>>3) + 144*(blk&7);            // XCD swizzle
  int b = rfl(g/288); int pbase = rfl(g - (g/288)*288)*32;
  int t = threadIdx.x;
  int l = t&63; int w = rfl(t>>6);
  int ln = l&15, q = l>>4;
  int grp = w>>1, c2w = w&1;
  int ow = w*2;                              // first 16-wide o-tile of this wave
  const f16* db0 = dscT + (size_t)b*HW*NC + c2w*32 + q*8;
  int gibase = b*9*HW + pbase + grp*16 + ln;
  float4 wvq[3]; ushort4 avq[3];
  uint4 GA[4], GB[4];                        // gather reg sets (parity)
  uint4 WA[2][2], WB2[2][2];                 // weight frag sets [nt][c2] (parity)
  v4f acc[2][2];
  #pragma unroll
  for (int mt=0;mt<2;mt++){ acc[mt][0]=(v4f){0,0,0,0}; acc[mt][1]=(v4f){0,0,0,0}; }

  auto gatherTo = [&](uint4* G, const ushort4& av, int s){
    const f16* d0 = db0 + (s&1)*64;
    G[0] = *(const uint4*)(d0 + (int)av.x*NC);
    G[1] = *(const uint4*)(d0 + (int)av.y*NC);
    G[2] = *(const uint4*)(d0 + (int)av.z*NC);
    G[3] = *(const uint4*)(d0 + (int)av.w*NC);
  };
  auto wloadTo = [&](uint4 Wt[2][2], int s){
    #pragma unroll
    for (int c2=0;c2<2;c2++){
      const f16* wp = wfr + (((s*2+c2)*8 + ow)*64 + l)*8;
      Wt[0][c2] = *(const uint4*)wp;
      Wt[1][c2] = *(const uint4*)(wp + 512);
    }
  };
  auto commitA = [&](int buf, uint4* G, const float4& wv){
    f16 hx=(f16)wv.x, hy=(f16)wv.y, hz=(f16)wv.z, hw=(f16)wv.w;
    h2v wx2={hx,hx}, wy2={hy,hy}, wz2={hz,hz}, ww2={hw,hw};
    unsigned ga[4],gb[4],gc[4],gd[4],ou[4];
    __builtin_memcpy(ga,&G[0],16); __builtin_memcpy(gb,&G[1],16);
    __builtin_memcpy(gc,&G[2],16); __builtin_memcpy(gd,&G[3],16);
    #pragma unroll
    for (int j=0;j<4;j++){
      h2v r = u2h2(ga[j])*wx2; r += u2h2(gb[j])*wy2;
      r += u2h2(gc[j])*wz2;    r += u2h2(gd[j])*ww2;
      unsigned uu; __builtin_memcpy(&uu,&r,4); ou[j]=uu;
    }
    uint4 pk; __builtin_memcpy(&pk,ou,16);
    *(uint4*)&As[buf][c2w][(grp*64 + l)*8] = pk;
  };
  auto mstep = [&](int buf, uint4 Wt[2][2]){
    #pragma unroll
    for (int c2=0;c2<2;c2++){
      half8 a0 = *(half8*)&As[buf][c2][(0*64+l)*8];
      half8 a1 = *(half8*)&As[buf][c2][(1*64+l)*8];
      #pragma unroll
      for (int nt=0;nt<2;nt++){
        half8 bw; __builtin_memcpy(&bw, &Wt[nt][c2], 16);
        acc[0][nt] = __builtin_amdgcn_mfma_f32_16x16x32_f16(a0, bw, acc[0][nt], 0,0,0);
        acc[1][nt] = __builtin_amdgcn_mfma_f32_16x16x32_f16(a1, bw, acc[1][nt], 0,0,0);
      }
    }
  };

  // prologue: coords for taps 0,1,2; steps 0,1 in flight; commit step 0
  wvq[0]=wg[gibase];       avq[0]=ad[gibase];
  wvq[1]=wg[gibase+HW];    avq[1]=ad[gibase+HW];
  wvq[2]=wg[gibase+2*HW];  avq[2]=ad[gibase+2*HW];
  gatherTo(GA, avq[0], 0); wloadTo(WA, 0);
  gatherTo(GB, avq[0], 1); wloadTo(WB2, 1);
  commitA(0, GA, wvq[0]);
  __syncthreads();
  #pragma unroll 3
  for (int tp=0; tp<9; tp++){
    int s = 2*tp;
    // even step s: M[s] on buf0/WA; issue G[s+2]/W[s+2]; commit C[s+1]
    if (tp<8) gatherTo(GA, avq[(tp+1)%3], s+2);
    mstep(0, WA);
    if (tp<8) wloadTo(WA, s+2);
    commitA(1, GB, wvq[tp%3]);
    __syncthreads();
    // odd step s+1: M[s+1] on buf1/WB2; issue G[s+3]/W[s+3]; commit C[s+2]
    if (tp<8) gatherTo(GB, avq[(tp+1)%3], s+3);
    mstep(1, WB2);
    if (tp<8) wloadTo(WB2, s+3);
    if (tp<8) commitA(0, GA, wvq[(tp+1)%3]);
    if (tp<=5){ int tn = tp+3;               // coords for tap tn -> slot tn%3 == tp%3
      wvq[tp%3]=wg[gibase+tn*HW]; avq[tp%3]=ad[gibase+tn*HW]; }
    __syncthreads();
  }
  #pragma unroll
  for (int nt=0;nt<2;nt++){
    int o = w*32 + nt*16 + ln;
    float bias = dc_b[o];
    #pragma unroll
    for (int mt=0;mt<2;mt++){
      #pragma unroll
      for (int r=0;r<4;r++){
        int px = pbase + mt*16 + q*4 + r;
        dc_t[((size_t)b*HW + px)*NC + o] = acc[mt][nt][r] + bias;
      }
    }
  }
}

// ---------------- K7: channel LayerNorm + sigmoid gate + multiply ----------------
__global__ __launch_bounds__(256) void epilogue(const float* __restrict__ dc_t,
    const float* __restrict__ dsc, const float* __restrict__ ln_g,
    const float* __restrict__ ln_b, float* __restrict__ out){
  __shared__ float T[64*129];
  __shared__ float Ps[4*64], Qs[4*64], Ms[64], Rs[64];
  int blk = blockIdx.x;
  int g = (blk>>3) + 72*(blk&7);
  int b = rfl(g/144); int pbase = rfl(g - (g/144)*144)*64;
  int t = threadIdx.x;
  #pragma unroll
  for (int i=0;i<8;i++){
    int idx = i*256 + t; int px = idx>>5, seg = idx&31;
    float4 v = *(const float4*)(dc_t + ((size_t)b*HW + pbase + px)*NC + seg*4);
    float* d = &T[px*129 + seg*4];
    d[0]=v.x; d[1]=v.y; d[2]=v.z; d[3]=v.w;
  }
  __syncthreads();
  int px = t&63, cg = t>>6;
  float s=0.f, ss=0.f;
  #pragma unroll
  for (int i=0;i<32;i++){ float v = T[px*129 + cg*32 + i]; s += v; ss = fmaf(v,v,ss); }
  Ps[cg*64+px] = s; Qs[cg*64+px] = ss;
  __syncthreads();
  if (t<64){
    float S = Ps[px]+Ps[64+px]+Ps[128+px]+Ps[192+px];
    float SS= Qs[px]+Qs[64+px]+Qs[128+px]+Qs[192+px];
    float m = S*(1.f/128.f);
    float var = SS*(1.f/128.f) - m*m;
    Ms[px] = m; Rs[px] = rsqrtf(var + 1e-5f);
  }
  __syncthreads();
  float m = Ms[px], rs = Rs[px];
  #pragma unroll 4
  for (int i=0;i<32;i++){
    int c = cg*32 + i;
    float ln = (T[px*129+c] - m)*rs*ln_g[c] + ln_b[c];
    float attn = 1.f/(1.f+__expf(-ln));
    size_t idx = (size_t)(b*NC+c)*HW + pbase + px;
    out[idx] = dsc[idx]*attn;
  }
}

extern "C" void kernel_launch(void* const* d_in, const int* in_sizes, int n_in,
                              void* d_out, int out_size, void* d_ws, size_t ws_size,
                              hipStream_t stream){
  const float* x    = (const float*)d_in[0];
  const float* dw_w = (const float*)d_in[1];
  const float* dw_b = (const float*)d_in[2];
  const float* pw_w = (const float*)d_in[3];
  const float* pw_b = (const float*)d_in[4];
  const float* off_w= (const float*)d_in[5];
  const float* off_b= (const float*)d_in[6];
  const float* dc_w = (const float*)d_in[7];
  const float* dc_b = (const float*)d_in[8];
  const float* ln_g = (const float*)d_in[9];
  const float* ln_b = (const float*)d_in[10];
  float* out = (float*)d_out;

  float* W    = (float*)d_ws;
  float*   bufA = W;                          // h1, then dsc (NCHW f32)
  float*   bufB = W + 4718592;                // h2, then dc_t (NHWC f32)
  f16*     dscT = (f16*)(W + 9437184);        // NHWC fp16 hi
  f16*     dscL = (f16*)(W + 11796480);       // NHWC fp16 lo residual
  float4*  wg   = (float4*)(W + 14155776);
  ushort4* ad   = (ushort4*)(W + 15482880);
  float*   st   = W + 16146432;
  f16*     wpwh = (f16*)(W + 16147456);
  f16*     wob  = (f16*)(W + 16155648);
  f16*     wfr  = (f16*)(W + 16174080);

  prep_weights<<<576, 256, 0, stream>>>(pw_w, off_w, dc_w, wpwh, wob, wfr);
  dw_conv     <<<18432, 256, 0, stream>>>(x, dw_w, dw_b, bufA);
  pw_mfma     <<<576, 256, 0, stream>>>(bufA, wpwh, pw_b, bufB);
  inorm_stats <<<512, 256, 0, stream>>>(bufB, st);
  make_dsc    <<<1152, 256, 0, stream>>>(bufB, st, bufA, dscT, dscL);
  off_mfma    <<<576, 256, 0, stream>>>(dscT, dscL, wob, off_b, wg, ad);
  deform_mfma <<<1152, 256, 0, stream>>>(dscT, wfr, dc_b, wg, ad, bufB);
  epilogue    <<<576, 256, 0, stream>>>(bufB, bufA, ln_g, ln_b, out);
}

// Round 7
// 251.738 us; speedup vs baseline: 1.1662x; 1.0100x over previous
//
#include <hip/hip_runtime.h>
#include <hip/hip_fp16.h>
#include <math.h>

#define HW 9216
#define WD 96
#define NC 128

typedef unsigned short u16;
typedef _Float16 f16;
typedef __attribute__((ext_vector_type(8))) _Float16 half8;
typedef __attribute__((ext_vector_type(2))) _Float16 h2v;
typedef __attribute__((ext_vector_type(4))) float v4f;

__device__ __forceinline__ int rfl(int v){ return __builtin_amdgcn_readfirstlane(v); }
__device__ __forceinline__ u16 h2u(f16 h){ u16 u; __builtin_memcpy(&u,&h,2); return u; }
__device__ __forceinline__ h2v u2h2(unsigned u){ h2v h; __builtin_memcpy(&h,&u,4); return h; }

// ---------------- K0: weight prep (all fp16) ----------------
// wpwh[o][c]
// wobf: offset-conv weights fragment-linear: step s=tap*4+cseg (32ch),
//   idx = ((s*2+nt)*64 + q*16+ln)*8 + j ; value w[o=nt*16+ln][tap*128+cseg*32+q*8+j] (o<18 else 0)
// wfr: deform weights fragment-linear: 64ch-block sw=tap*2+hi, half c2,
//   idx = (((sw*2+c2)*8 + nt)*64 + q*16+ln)*8 + j
__global__ __launch_bounds__(256) void prep_weights(const float* __restrict__ pw_w,
    const float* __restrict__ off_w, const float* __restrict__ dc_w,
    f16* __restrict__ wpwh, f16* __restrict__ wobf, f16* __restrict__ wfr){
  int t = blockIdx.x*256 + threadIdx.x;
  if (t < 16384) wpwh[t] = (f16)pw_w[t];
  if (t < 36864){
    int o = t/1152, k_lin = t - o*1152;
    int tap = k_lin>>7;
    int s = k_lin>>5, q = (k_lin>>3)&3, j = k_lin&7;
    int idx = ((s*2 + (o>>4))*64 + q*16 + (o&15))*8 + j;
    wobf[idx] = (o<18) ? (f16)off_w[(o*128 + (k_lin&127))*9 + tap] : (f16)0.f;
  }
  if (t < 147456){
    int o = t/1152, k_lin = t - o*1152;
    int tap = k_lin>>7, c = k_lin&127;
    int sw = k_lin>>6, c2 = (k_lin>>5)&1, qw = (k_lin>>3)&3, j = k_lin&7;
    int idx = (((sw*2 + c2)*8 + (o>>4))*64 + qw*16 + (o&15))*8 + j;
    wfr[idx] = (f16)dc_w[(o*128+c)*9 + tap];
  }
}

// ---------------- K1: depthwise 3x3 + bias (NCHW fp32) ----------------
__global__ __launch_bounds__(256) void dw_conv(const float* __restrict__ x,
    const float* __restrict__ w, const float* __restrict__ bias, float* __restrict__ h1){
  int n = blockIdx.x*256 + threadIdx.x;
  int bc = rfl(n / HW);
  int p = n - bc*HW;
  int c = bc & 127;
  int yy = p / WD, xx = p - (p/WD)*WD;
  const float* xc = x + (size_t)bc*HW;
  float acc = bias[c];
  #pragma unroll
  for (int r=0;r<3;r++){
    int y2 = yy + r - 1;
    #pragma unroll
    for (int cc2=0;cc2<3;cc2++){
      int x2 = xx + cc2 - 1;
      if (y2>=0 && y2<96 && x2>=0 && x2<96)
        acc = fmaf(w[c*9 + r*3 + cc2], xc[y2*WD + x2], acc);
    }
  }
  h1[n] = acc;
}

// ---------------- K2: pointwise 1x1 via MFMA (fp16) ----------------
__global__ __launch_bounds__(256) void pw_mfma(const float* __restrict__ h1,
    const f16* __restrict__ wpwh, const float* __restrict__ pw_b, float* __restrict__ h2){
  __shared__ f16 Aw[128*136];
  __shared__ f16 Bw[128*68];
  int blk = blockIdx.x; int row0 = blk*64;
  int b = rfl(row0/HW); int pbase = rfl(row0 - b*HW);
  int t = threadIdx.x;
  #pragma unroll
  for (int i=0;i<8;i++){
    int idx = i*256 + t; int o = idx>>4, seg = idx&15;
    *(half8*)&Aw[o*136 + seg*8] = *(const half8*)(wpwh + o*128 + seg*8);
  }
  #pragma unroll
  for (int i=0;i<8;i++){
    int idx = i*256 + t; int c = idx>>4, seg = idx&15;
    float4 v = *(const float4*)(h1 + (size_t)(b*NC+c)*HW + pbase + seg*4);
    ushort4 pk = make_ushort4(h2u((f16)v.x), h2u((f16)v.y), h2u((f16)v.z), h2u((f16)v.w));
    *(ushort4*)&Bw[c*68 + seg*4] = pk;
  }
  __syncthreads();
  int w = rfl(t>>6); int l = t&63; int q = l>>4; int ln = l&15;
  v4f acc[8];
  #pragma unroll
  for (int mt=0;mt<8;mt++) acc[mt] = (v4f){0.f,0.f,0.f,0.f};
  #pragma unroll
  for (int ks=0;ks<4;ks++){
    half8 bf;
    #pragma unroll
    for (int j=0;j<8;j++) bf[j] = Bw[(ks*32 + q*8 + j)*68 + w*16 + ln];
    #pragma unroll
    for (int mt=0;mt<8;mt++){
      half8 af = *(half8*)&Aw[(mt*16+ln)*136 + ks*32 + q*8];
      acc[mt] = __builtin_amdgcn_mfma_f32_16x16x32_f16(af, bf, acc[mt], 0,0,0);
    }
  }
  int px = pbase + w*16 + ln;
  #pragma unroll
  for (int mt=0;mt<8;mt++){
    #pragma unroll
    for (int r=0;r<4;r++){
      int o = mt*16 + q*4 + r;
      h2[(size_t)(b*NC+o)*HW + px] = acc[mt][r] + pw_b[o];
    }
  }
}

// ---------------- K3: InstanceNorm stats ----------------
__global__ __launch_bounds__(256) void inorm_stats(const float* __restrict__ h2, float* __restrict__ st){
  int bc = blockIdx.x;
  const float* src = h2 + (size_t)bc*HW;
  float s=0.f, ss=0.f;
  for (int i=threadIdx.x; i<HW; i+=256){ float v=src[i]; s+=v; ss=fmaf(v,v,ss); }
  #pragma unroll
  for (int off=32; off; off>>=1){ s += __shfl_down(s,off); ss += __shfl_down(ss,off); }
  __shared__ float rsm[2][4];
  int wave = threadIdx.x>>6, lane = threadIdx.x&63;
  if (lane==0){ rsm[0][wave]=s; rsm[1][wave]=ss; }
  __syncthreads();
  if (threadIdx.x==0){
    float S = rsm[0][0]+rsm[0][1]+rsm[0][2]+rsm[0][3];
    float SS= rsm[1][0]+rsm[1][1]+rsm[1][2]+rsm[1][3];
    float mu = S * (1.f/9216.f);
    float var = SS * (1.f/9216.f) - mu*mu;
    st[bc*2]   = mu;
    st[bc*2+1] = rsqrtf(var + 1e-5f);
  }
}

// ---------------- K4: dsc (NCHW fp32) + dscT (NHWC fp16) ----------------
__global__ __launch_bounds__(256) void make_dsc(const float* __restrict__ h2,
    const float* __restrict__ st, float* __restrict__ dsc, f16* __restrict__ dscT){
  int blk = blockIdx.x;
  int pt = blk % 144; int r = blk/144; int ch = r & 1; int b = r >> 1;
  int c0 = ch*64, pbase = pt*64;
  __shared__ float tile[64][65];
  int tr = threadIdx.x >> 2;
  int g  = threadIdx.x & 3;
  int c  = c0 + tr;
  float mu = st[(b*128+c)*2];
  float rs = st[(b*128+c)*2+1];
  const float* src = h2 + (size_t)(b*128+c)*HW + pbase + g*16;
  float* d = dsc + (size_t)(b*128+c)*HW + pbase + g*16;
  #pragma unroll
  for (int i=0;i<4;i++){
    float4 v = *(const float4*)(src + i*4);
    v.x=(v.x-mu)*rs; v.y=(v.y-mu)*rs; v.z=(v.z-mu)*rs; v.w=(v.w-mu)*rs;
    *(float4*)(d + i*4) = v;
    tile[tr][g*16+i*4+0]=v.x; tile[tr][g*16+i*4+1]=v.y;
    tile[tr][g*16+i*4+2]=v.z; tile[tr][g*16+i*4+3]=v.w;
  }
  __syncthreads();
  int pr = tr;
  f16* dt = dscT + ((size_t)b*HW + pbase + pr)*NC + c0 + g*16;
  #pragma unroll
  for (int i=0;i<4;i++){
    *(ushort4*)(dt + i*4) = make_ushort4(
      h2u((f16)tile[g*16+i*4+0][pr]), h2u((f16)tile[g*16+i*4+1][pr]),
      h2u((f16)tile[g*16+i*4+2][pr]), h2u((f16)tile[g*16+i*4+3][pr]));
  }
}

// ---------------- K5: offset conv via MFMA — barrier-free K-loop + bilinear precomp ----
// Wave w owns m-tile w (16px) for full K; o=0..31 (nt 0,1). A-frag = direct tap load.
__global__ __launch_bounds__(256) void off_mfma(const f16* __restrict__ dscT,
    const f16* __restrict__ wobf, const float* __restrict__ off_b,
    float4* __restrict__ wg, ushort4* __restrict__ ad){
  __shared__ float Po[18*64];
  int blk = blockIdx.x;
  int g = (blk>>3) + 72*(blk&7);
  int b = rfl(g/144); int pbase = rfl(g - (g/144)*144)*64;
  int t = threadIdx.x;
  int l = t&63; int w = rfl(t>>6);
  int ln = l&15, q = l>>4;
  int P = pbase + w*16 + ln;
  int py = P/96, pxx = P - 96*(P/96);
  const f16* hib = dscT + (size_t)b*HW*NC + q*8;
  const uint4 Z = (uint4){0,0,0,0};
  uint4 Gf[3]; uint4 Wf[2][2];
  v4f acc[2];
  acc[0] = (v4f){0.f,0.f,0.f,0.f}; acc[1] = (v4f){0.f,0.f,0.f,0.f};
  auto gatherO = [&](uint4& G, int s){
    int tap = s>>2, cb = (s&3)*32;
    int y2 = py + tap/3 - 1, x2 = pxx + tap%3 - 1;
    bool valid = ((unsigned)y2 < 96u) && ((unsigned)x2 < 96u);
    G = valid ? *(const uint4*)(hib + (y2*96 + x2)*NC + cb) : Z;
  };
  auto wloadO = [&](uint4* Wt, int s){
    const f16* wp = wobf + (s*2*64 + l)*8;
    Wt[0] = *(const uint4*)wp;
    Wt[1] = *(const uint4*)(wp + 512);
  };
  gatherO(Gf[0],0); gatherO(Gf[1],1); gatherO(Gf[2],2);
  wloadO(Wf[0],0); wloadO(Wf[1],1);
  #pragma unroll
  for (int s=0;s<36;s++){
    half8 af, b0, b1;
    __builtin_memcpy(&af,&Gf[s%3],16);
    __builtin_memcpy(&b0,&Wf[s&1][0],16);
    __builtin_memcpy(&b1,&Wf[s&1][1],16);
    acc[0] = __builtin_amdgcn_mfma_f32_16x16x32_f16(af, b0, acc[0], 0,0,0);
    acc[1] = __builtin_amdgcn_mfma_f32_16x16x32_f16(af, b1, acc[1], 0,0,0);
    if (s<33) gatherO(Gf[s%3], s+3);
    if (s<34) wloadO(Wf[s&1], s+2);
  }
  #pragma unroll
  for (int nt=0;nt<2;nt++){
    int o = nt*16 + ln;
    if (o < 18){
      float obias = off_b[o];
      #pragma unroll
      for (int r=0;r<4;r++) Po[o*64 + w*16 + q*4 + r] = acc[nt][r] + obias;
    }
  }
  __syncthreads();
  #pragma unroll
  for (int i=0;i<3;i++){
    int idx = i*256 + t;
    if (idx < 576){
      int pxl = idx & 63, k = idx >> 6;
      int Pp = pbase + pxl;
      float dy = Po[(2*k)*64 + pxl], dx = Po[(2*k+1)*64 + pxl];
      float ys = (float)(Pp/96 + k/3 - 1) + dy;
      float xs = (float)(Pp%96 + k%3 - 1) + dx;
      float fy0 = floorf(ys), fx0 = floorf(xs);
      float wy = ys - fy0, wx = xs - fx0;
      int y0 = (int)fy0, x0 = (int)fx0;
      int y1 = y0+1, x1 = x0+1;
      float vy0 = (y0>=0 && y0<=95) ? 1.f : 0.f;
      float vy1 = (y1>=0 && y1<=95) ? 1.f : 0.f;
      float vx0 = (x0>=0 && x0<=95) ? 1.f : 0.f;
      float vx1 = (x1>=0 && x1<=95) ? 1.f : 0.f;
      int y0c=min(max(y0,0),95), y1c=min(max(y1,0),95);
      int x0c=min(max(x0,0),95), x1c=min(max(x1,0),95);
      float4 w4;
      w4.x = (1.f-wy)*(1.f-wx)*vy0*vx0;
      w4.y = (1.f-wy)*wx*vy0*vx1;
      w4.z = wy*(1.f-wx)*vy1*vx0;
      w4.w = wy*wx*vy1*vx1;
      int gi = (b*9 + k)*HW + pbase + pxl;
      wg[gi] = w4;
      ad[gi] = make_ushort4((u16)(y0c*WD+x0c), (u16)(y0c*WD+x1c),
                            (u16)(y1c*WD+x0c), (u16)(y1c*WD+x1c));
    }
  }
}

// ---------------- K6: deform conv — barrier-free K-loop ----------------
// 32px x 128o blocks. Wave (grp=w>>1, c2w=w&1): gathers 16px x its 32-ch half,
// own gather IS the A-frag; 8 MFMAs (full o=128) per step vs fragment-linear wfr.
// Partner-wave K-halves summed once at the end via LDS.
__global__ __launch_bounds__(256) void deform_mfma(const f16* __restrict__ dscT,
    const f16* __restrict__ wfr, const float* __restrict__ dc_b,
    const float4* __restrict__ wg, const ushort4* __restrict__ ad,
    float* __restrict__ dc_t){
  __shared__ float Red[2][2112];             // [grp][l*33 + nt*4 + r]
  int blk = blockIdx.x;                      // 1152
  int g = (blk>>3) + 144*(blk&7);            // XCD swizzle
  int b = rfl(g/288); int pbase = rfl(g - (g/288)*288)*32;
  int t = threadIdx.x;
  int l = t&63; int w = rfl(t>>6);
  int ln = l&15, q = l>>4;
  int grp = w>>1, c2w = w&1;
  const f16* db0 = dscT + (size_t)b*HW*NC + c2w*32 + q*8;
  int gibase = b*9*HW + pbase + grp*16 + ln;
  float4 wvq[3]; ushort4 avq[3];
  uint4 G[3][4]; uint4 W2[2][8];
  v4f acc[8];
  #pragma unroll
  for (int nt=0;nt<8;nt++) acc[nt] = (v4f){0.f,0.f,0.f,0.f};
  auto gatherTo = [&](uint4* Gd, const ushort4& av, int s){
    const f16* d0 = db0 + (s&1)*64;
    Gd[0] = *(const uint4*)(d0 + (int)av.x*NC);
    Gd[1] = *(const uint4*)(d0 + (int)av.y*NC);
    Gd[2] = *(const uint4*)(d0 + (int)av.z*NC);
    Gd[3] = *(const uint4*)(d0 + (int)av.w*NC);
  };
  auto wloadTo = [&](uint4* Wt, int s){
    const f16* wp = wfr + (((s*2 + c2w)*8)*64 + l)*8;
    #pragma unroll
    for (int nt=0;nt<8;nt++) Wt[nt] = *(const uint4*)(wp + nt*512);
  };
  auto mstep = [&](uint4* Gd, const float4& wv, uint4* Wt){
    f16 hx=(f16)wv.x, hy=(f16)wv.y, hz=(f16)wv.z, hw=(f16)wv.w;
    h2v wx2={hx,hx}, wy2={hy,hy}, wz2={hz,hz}, ww2={hw,hw};
    unsigned ga[4],gb[4],gc[4],gd[4],ou[4];
    __builtin_memcpy(ga,&Gd[0],16); __builtin_memcpy(gb,&Gd[1],16);
    __builtin_memcpy(gc,&Gd[2],16); __builtin_memcpy(gd,&Gd[3],16);
    #pragma unroll
    for (int j=0;j<4;j++){
      h2v r = u2h2(ga[j])*wx2; r += u2h2(gb[j])*wy2;
      r += u2h2(gc[j])*wz2;    r += u2h2(gd[j])*ww2;
      unsigned uu; __builtin_memcpy(&uu,&r,4); ou[j]=uu;
    }
    uint4 pk; __builtin_memcpy(&pk,ou,16);
    half8 af; __builtin_memcpy(&af,&pk,16);
    #pragma unroll
    for (int nt=0;nt<8;nt++){
      half8 bw; __builtin_memcpy(&bw,&Wt[nt],16);
      acc[nt] = __builtin_amdgcn_mfma_f32_16x16x32_f16(af, bw, acc[nt], 0,0,0);
    }
  };
  // prologue: coords taps 0..2; gathers steps 0..2; weights steps 0,1
  wvq[0]=wg[gibase];       avq[0]=ad[gibase];
  wvq[1]=wg[gibase+HW];    avq[1]=ad[gibase+HW];
  wvq[2]=wg[gibase+2*HW];  avq[2]=ad[gibase+2*HW];
  gatherTo(G[0], avq[0], 0);
  gatherTo(G[1], avq[0], 1);
  gatherTo(G[2], avq[1], 2);
  wloadTo(W2[0], 0); wloadTo(W2[1], 1);
  #pragma unroll
  for (int s=0;s<18;s++){
    int tp = s>>1;
    mstep(G[s%3], wvq[tp%3], W2[s&1]);
    if (s<15) gatherTo(G[s%3], avq[((s+3)>>1)%3], s+3);
    if (s<16) wloadTo(W2[s&1], s+2);
    if ((s&1)==1 && tp<6){
      wvq[tp%3]=wg[gibase+(tp+3)*HW]; avq[tp%3]=ad[gibase+(tp+3)*HW];
    }
  }
  // cross-wave K-half reduction + store
  if (c2w==1){
    #pragma unroll
    for (int nt=0;nt<8;nt++)
      #pragma unroll
      for (int r=0;r<4;r++) Red[grp][l*33 + nt*4 + r] = acc[nt][r];
  }
  __syncthreads();
  if (c2w==0){
    #pragma unroll
    for (int nt=0;nt<8;nt++){
      float bias = dc_b[nt*16 + ln];
      #pragma unroll
      for (int r=0;r<4;r++){
        int px = pbase + grp*16 + q*4 + r;
        float v = acc[nt][r] + Red[grp][l*33 + nt*4 + r] + bias;
        dc_t[((size_t)b*HW + px)*NC + nt*16 + ln] = v;
      }
    }
  }
}

// ---------------- K7: channel LayerNorm + sigmoid gate + multiply ----------------
__global__ __launch_bounds__(256) void epilogue(const float* __restrict__ dc_t,
    const float* __restrict__ dsc, const float* __restrict__ ln_g,
    const float* __restrict__ ln_b, float* __restrict__ out){
  __shared__ float T[64*129];
  __shared__ float Ps[4*64], Qs[4*64], Ms[64], Rs[64];
  int blk = blockIdx.x;
  int g = (blk>>3) + 72*(blk&7);
  int b = rfl(g/144); int pbase = rfl(g - (g/144)*144)*64;
  int t = threadIdx.x;
  #pragma unroll
  for (int i=0;i<8;i++){
    int idx = i*256 + t; int px = idx>>5, seg = idx&31;
    float4 v = *(const float4*)(dc_t + ((size_t)b*HW + pbase + px)*NC + seg*4);
    float* d = &T[px*129 + seg*4];
    d[0]=v.x; d[1]=v.y; d[2]=v.z; d[3]=v.w;
  }
  __syncthreads();
  int px = t&63, cg = t>>6;
  float s=0.f, ss=0.f;
  #pragma unroll
  for (int i=0;i<32;i++){ float v = T[px*129 + cg*32 + i]; s += v; ss = fmaf(v,v,ss); }
  Ps[cg*64+px] = s; Qs[cg*64+px] = ss;
  __syncthreads();
  if (t<64){
    float S = Ps[px]+Ps[64+px]+Ps[128+px]+Ps[192+px];
    float SS= Qs[px]+Qs[64+px]+Qs[128+px]+Qs[192+px];
    float m = S*(1.f/128.f);
    float var = SS*(1.f/128.f) - m*m;
    Ms[px] = m; Rs[px] = rsqrtf(var + 1e-5f);
  }
  __syncthreads();
  float m = Ms[px], rs = Rs[px];
  #pragma unroll 4
  for (int i=0;i<32;i++){
    int c = cg*32 + i;
    float ln = (T[px*129+c] - m)*rs*ln_g[c] + ln_b[c];
    float attn = 1.f/(1.f+__expf(-ln));
    size_t idx = (size_t)(b*NC+c)*HW + pbase + px;
    out[idx] = dsc[idx]*attn;
  }
}

extern "C" void kernel_launch(void* const* d_in, const int* in_sizes, int n_in,
                              void* d_out, int out_size, void* d_ws, size_t ws_size,
                              hipStream_t stream){
  const float* x    = (const float*)d_in[0];
  const float* dw_w = (const float*)d_in[1];
  const float* dw_b = (const float*)d_in[2];
  const float* pw_w = (const float*)d_in[3];
  const float* pw_b = (const float*)d_in[4];
  const float* off_w= (const float*)d_in[5];
  const float* off_b= (const float*)d_in[6];
  const float* dc_w = (const float*)d_in[7];
  const float* dc_b = (const float*)d_in[8];
  const float* ln_g = (const float*)d_in[9];
  const float* ln_b = (const float*)d_in[10];
  float* out = (float*)d_out;

  float* W    = (float*)d_ws;
  float*   bufA = W;                          // h1, then dsc (NCHW f32)
  float*   bufB = W + 4718592;                // h2, then dc_t (NHWC f32)
  f16*     dscT = (f16*)(W + 9437184);        // NHWC fp16
  float4*  wg   = (float4*)(W + 14155776);
  ushort4* ad   = (ushort4*)(W + 15482880);
  float*   st   = W + 16146432;
  f16*     wpwh = (f16*)(W + 16147456);
  f16*     wobf = (f16*)(W + 16155648);
  f16*     wfr  = (f16*)(W + 16174080);

  prep_weights<<<576, 256, 0, stream>>>(pw_w, off_w, dc_w, wpwh, wobf, wfr);
  dw_conv     <<<18432, 256, 0, stream>>>(x, dw_w, dw_b, bufA);
  pw_mfma     <<<576, 256, 0, stream>>>(bufA, wpwh, pw_b, bufB);
  inorm_stats <<<512, 256, 0, stream>>>(bufB, st);
  make_dsc    <<<1152, 256, 0, stream>>>(bufB, st, bufA, dscT);
  off_mfma    <<<576, 256, 0, stream>>>(dscT, wobf, off_b, wg, ad);
  deform_mfma <<<1152, 256, 0, stream>>>(dscT, wfr, dc_b, wg, ad, bufB);
  epilogue    <<<576, 256, 0, stream>>>(bufB, bufA, ln_g, ln_b, out);
}

// Round 8
// 250.358 us; speedup vs baseline: 1.1726x; 1.0055x over previous
//
#include <hip/hip_runtime.h>
#include <hip/hip_fp16.h>
#include <math.h>

#define HW 9216
#define WD 96
#define NC 128

typedef unsigned short u16;
typedef _Float16 f16;
typedef __attribute__((ext_vector_type(8))) _Float16 half8;
typedef __attribute__((ext_vector_type(2))) _Float16 h2v;
typedef __attribute__((ext_vector_type(4))) float v4f;

__device__ __forceinline__ int rfl(int v){ return __builtin_amdgcn_readfirstlane(v); }
__device__ __forceinline__ u16 h2u(f16 h){ u16 u; __builtin_memcpy(&u,&h,2); return u; }
__device__ __forceinline__ h2v u2h2(unsigned u){ h2v h; __builtin_memcpy(&h,&u,4); return h; }

// ---------------- K0: weight prep (all fp16) ----------------
__global__ __launch_bounds__(256) void prep_weights(const float* __restrict__ pw_w,
    const float* __restrict__ off_w, const float* __restrict__ dc_w,
    f16* __restrict__ wpwh, f16* __restrict__ wobf, f16* __restrict__ wfr){
  int t = blockIdx.x*256 + threadIdx.x;
  if (t < 16384) wpwh[t] = (f16)pw_w[t];
  if (t < 36864){
    int o = t/1152, k_lin = t - o*1152;
    int tap = k_lin>>7;
    int s = k_lin>>5, q = (k_lin>>3)&3, j = k_lin&7;
    int idx = ((s*2 + (o>>4))*64 + q*16 + (o&15))*8 + j;
    wobf[idx] = (o<18) ? (f16)off_w[(o*128 + (k_lin&127))*9 + tap] : (f16)0.f;
  }
  if (t < 147456){
    int o = t/1152, k_lin = t - o*1152;
    int tap = k_lin>>7, c = k_lin&127;
    int sw = k_lin>>6, c2 = (k_lin>>5)&1, qw = (k_lin>>3)&3, j = k_lin&7;
    int idx = (((sw*2 + c2)*8 + (o>>4))*64 + qw*16 + (o&15))*8 + j;
    wfr[idx] = (f16)dc_w[(o*128+c)*9 + tap];
  }
}

// ---------------- K1: depthwise 3x3 + bias (NCHW fp32) ----------------
__global__ __launch_bounds__(256) void dw_conv(const float* __restrict__ x,
    const float* __restrict__ w, const float* __restrict__ bias, float* __restrict__ h1){
  int n = blockIdx.x*256 + threadIdx.x;
  int bc = rfl(n / HW);
  int p = n - bc*HW;
  int c = bc & 127;
  int yy = p / WD, xx = p - (p/WD)*WD;
  const float* xc = x + (size_t)bc*HW;
  float acc = bias[c];
  #pragma unroll
  for (int r=0;r<3;r++){
    int y2 = yy + r - 1;
    #pragma unroll
    for (int cc2=0;cc2<3;cc2++){
      int x2 = xx + cc2 - 1;
      if (y2>=0 && y2<96 && x2>=0 && x2<96)
        acc = fmaf(w[c*9 + r*3 + cc2], xc[y2*WD + x2], acc);
    }
  }
  h1[n] = acc;
}

// ---------------- K2: pointwise 1x1 via MFMA (fp16) ----------------
__global__ __launch_bounds__(256) void pw_mfma(const float* __restrict__ h1,
    const f16* __restrict__ wpwh, const float* __restrict__ pw_b, float* __restrict__ h2){
  __shared__ f16 Aw[128*136];
  __shared__ f16 Bw[128*68];
  int blk = blockIdx.x; int row0 = blk*64;
  int b = rfl(row0/HW); int pbase = rfl(row0 - b*HW);
  int t = threadIdx.x;
  #pragma unroll
  for (int i=0;i<8;i++){
    int idx = i*256 + t; int o = idx>>4, seg = idx&15;
    *(half8*)&Aw[o*136 + seg*8] = *(const half8*)(wpwh + o*128 + seg*8);
  }
  #pragma unroll
  for (int i=0;i<8;i++){
    int idx = i*256 + t; int c = idx>>4, seg = idx&15;
    float4 v = *(const float4*)(h1 + (size_t)(b*NC+c)*HW + pbase + seg*4);
    ushort4 pk = make_ushort4(h2u((f16)v.x), h2u((f16)v.y), h2u((f16)v.z), h2u((f16)v.w));
    *(ushort4*)&Bw[c*68 + seg*4] = pk;
  }
  __syncthreads();
  int w = rfl(t>>6); int l = t&63; int q = l>>4; int ln = l&15;
  v4f acc[8];
  #pragma unroll
  for (int mt=0;mt<8;mt++) acc[mt] = (v4f){0.f,0.f,0.f,0.f};
  #pragma unroll
  for (int ks=0;ks<4;ks++){
    half8 bf;
    #pragma unroll
    for (int j=0;j<8;j++) bf[j] = Bw[(ks*32 + q*8 + j)*68 + w*16 + ln];
    #pragma unroll
    for (int mt=0;mt<8;mt++){
      half8 af = *(half8*)&Aw[(mt*16+ln)*136 + ks*32 + q*8];
      acc[mt] = __builtin_amdgcn_mfma_f32_16x16x32_f16(af, bf, acc[mt], 0,0,0);
    }
  }
  int px = pbase + w*16 + ln;
  #pragma unroll
  for (int mt=0;mt<8;mt++){
    #pragma unroll
    for (int r=0;r<4;r++){
      int o = mt*16 + q*4 + r;
      h2[(size_t)(b*NC+o)*HW + px] = acc[mt][r] + pw_b[o];
    }
  }
}

// ---------------- K3: InstanceNorm stats ----------------
__global__ __launch_bounds__(256) void inorm_stats(const float* __restrict__ h2, float* __restrict__ st){
  int bc = blockIdx.x;
  const float* src = h2 + (size_t)bc*HW;
  float s=0.f, ss=0.f;
  for (int i=threadIdx.x; i<HW; i+=256){ float v=src[i]; s+=v; ss=fmaf(v,v,ss); }
  #pragma unroll
  for (int off=32; off; off>>=1){ s += __shfl_down(s,off); ss += __shfl_down(ss,off); }
  __shared__ float rsm[2][4];
  int wave = threadIdx.x>>6, lane = threadIdx.x&63;
  if (lane==0){ rsm[0][wave]=s; rsm[1][wave]=ss; }
  __syncthreads();
  if (threadIdx.x==0){
    float S = rsm[0][0]+rsm[0][1]+rsm[0][2]+rsm[0][3];
    float SS= rsm[1][0]+rsm[1][1]+rsm[1][2]+rsm[1][3];
    float mu = S * (1.f/9216.f);
    float var = SS * (1.f/9216.f) - mu*mu;
    st[bc*2]   = mu;
    st[bc*2+1] = rsqrtf(var + 1e-5f);
  }
}

// ---------------- K4: dsc (NCHW fp32) + dscT (NHWC fp16) ----------------
__global__ __launch_bounds__(256) void make_dsc(const float* __restrict__ h2,
    const float* __restrict__ st, float* __restrict__ dsc, f16* __restrict__ dscT){
  int blk = blockIdx.x;
  int pt = blk % 144; int r = blk/144; int ch = r & 1; int b = r >> 1;
  int c0 = ch*64, pbase = pt*64;
  __shared__ float tile[64][65];
  int tr = threadIdx.x >> 2;
  int g  = threadIdx.x & 3;
  int c  = c0 + tr;
  float mu = st[(b*128+c)*2];
  float rs = st[(b*128+c)*2+1];
  const float* src = h2 + (size_t)(b*128+c)*HW + pbase + g*16;
  float* d = dsc + (size_t)(b*128+c)*HW + pbase + g*16;
  #pragma unroll
  for (int i=0;i<4;i++){
    float4 v = *(const float4*)(src + i*4);
    v.x=(v.x-mu)*rs; v.y=(v.y-mu)*rs; v.z=(v.z-mu)*rs; v.w=(v.w-mu)*rs;
    *(float4*)(d + i*4) = v;
    tile[tr][g*16+i*4+0]=v.x; tile[tr][g*16+i*4+1]=v.y;
    tile[tr][g*16+i*4+2]=v.z; tile[tr][g*16+i*4+3]=v.w;
  }
  __syncthreads();
  int pr = tr;
  f16* dt = dscT + ((size_t)b*HW + pbase + pr)*NC + c0 + g*16;
  #pragma unroll
  for (int i=0;i<4;i++){
    *(ushort4*)(dt + i*4) = make_ushort4(
      h2u((f16)tile[g*16+i*4+0][pr]), h2u((f16)tile[g*16+i*4+1][pr]),
      h2u((f16)tile[g*16+i*4+2][pr]), h2u((f16)tile[g*16+i*4+3][pr]));
  }
}

// ---------------- K5: offset conv via MFMA — barrier-free K-loop + bilinear precomp ----
__global__ __launch_bounds__(256) void off_mfma(const f16* __restrict__ dscT,
    const f16* __restrict__ wobf, const float* __restrict__ off_b,
    float4* __restrict__ wg, ushort4* __restrict__ ad){
  __shared__ float Po[18*64];
  int blk = blockIdx.x;
  int g = (blk>>3) + 72*(blk&7);
  int b = rfl(g/144); int pbase = rfl(g - (g/144)*144)*64;
  int t = threadIdx.x;
  int l = t&63; int w = rfl(t>>6);
  int ln = l&15, q = l>>4;
  int P = pbase + w*16 + ln;
  int py = P/96, pxx = P - 96*(P/96);
  const f16* hib = dscT + (size_t)b*HW*NC + q*8;
  const uint4 Z = (uint4){0,0,0,0};
  uint4 Gf[3]; uint4 Wf[2][2];
  v4f acc[2];
  acc[0] = (v4f){0.f,0.f,0.f,0.f}; acc[1] = (v4f){0.f,0.f,0.f,0.f};
  auto gatherO = [&](uint4& G, int s){
    int tap = s>>2, cb = (s&3)*32;
    int y2 = py + tap/3 - 1, x2 = pxx + tap%3 - 1;
    bool valid = ((unsigned)y2 < 96u) && ((unsigned)x2 < 96u);
    G = valid ? *(const uint4*)(hib + (y2*96 + x2)*NC + cb) : Z;
  };
  auto wloadO = [&](uint4* Wt, int s){
    const f16* wp = wobf + (s*2*64 + l)*8;
    Wt[0] = *(const uint4*)wp;
    Wt[1] = *(const uint4*)(wp + 512);
  };
  gatherO(Gf[0],0); gatherO(Gf[1],1); gatherO(Gf[2],2);
  wloadO(Wf[0],0); wloadO(Wf[1],1);
  #pragma unroll
  for (int s=0;s<36;s++){
    half8 af, b0, b1;
    __builtin_memcpy(&af,&Gf[s%3],16);
    __builtin_memcpy(&b0,&Wf[s&1][0],16);
    __builtin_memcpy(&b1,&Wf[s&1][1],16);
    acc[0] = __builtin_amdgcn_mfma_f32_16x16x32_f16(af, b0, acc[0], 0,0,0);
    acc[1] = __builtin_amdgcn_mfma_f32_16x16x32_f16(af, b1, acc[1], 0,0,0);
    if (s<33) gatherO(Gf[s%3], s+3);
    if (s<34) wloadO(Wf[s&1], s+2);
  }
  #pragma unroll
  for (int nt=0;nt<2;nt++){
    int o = nt*16 + ln;
    if (o < 18){
      float obias = off_b[o];
      #pragma unroll
      for (int r=0;r<4;r++) Po[o*64 + w*16 + q*4 + r] = acc[nt][r] + obias;
    }
  }
  __syncthreads();
  #pragma unroll
  for (int i=0;i<3;i++){
    int idx = i*256 + t;
    if (idx < 576){
      int pxl = idx & 63, k = idx >> 6;
      int Pp = pbase + pxl;
      float dy = Po[(2*k)*64 + pxl], dx = Po[(2*k+1)*64 + pxl];
      float ys = (float)(Pp/96 + k/3 - 1) + dy;
      float xs = (float)(Pp%96 + k%3 - 1) + dx;
      float fy0 = floorf(ys), fx0 = floorf(xs);
      float wy = ys - fy0, wx = xs - fx0;
      int y0 = (int)fy0, x0 = (int)fx0;
      int y1 = y0+1, x1 = x0+1;
      float vy0 = (y0>=0 && y0<=95) ? 1.f : 0.f;
      float vy1 = (y1>=0 && y1<=95) ? 1.f : 0.f;
      float vx0 = (x0>=0 && x0<=95) ? 1.f : 0.f;
      float vx1 = (x1>=0 && x1<=95) ? 1.f : 0.f;
      int y0c=min(max(y0,0),95), y1c=min(max(y1,0),95);
      int x0c=min(max(x0,0),95), x1c=min(max(x1,0),95);
      float4 w4;
      w4.x = (1.f-wy)*(1.f-wx)*vy0*vx0;
      w4.y = (1.f-wy)*wx*vy0*vx1;
      w4.z = wy*(1.f-wx)*vy1*vx0;
      w4.w = wy*wx*vy1*vx1;
      int gi = (b*9 + k)*HW + pbase + pxl;
      wg[gi] = w4;
      ad[gi] = make_ushort4((u16)(y0c*WD+x0c), (u16)(y0c*WD+x1c),
                            (u16)(y1c*WD+x0c), (u16)(y1c*WD+x1c));
    }
  }
}

// ---------------- K6: deform conv — barrier-free K-loop ----------------
// ONLY change vs R7: __launch_bounds__(256, 2) -> 256-VGPR budget so the
// depth-3 gather / depth-2 weight pipeline actually lives in registers
// (R7's VGPR_Count=64 proved the compiler spilled/serialized it).
__global__ __launch_bounds__(256, 2) void deform_mfma(const f16* __restrict__ dscT,
    const f16* __restrict__ wfr, const float* __restrict__ dc_b,
    const float4* __restrict__ wg, const ushort4* __restrict__ ad,
    float* __restrict__ dc_t){
  __shared__ float Red[2][2112];             // [grp][l*33 + nt*4 + r]
  int blk = blockIdx.x;                      // 1152
  int g = (blk>>3) + 144*(blk&7);            // XCD swizzle
  int b = rfl(g/288); int pbase = rfl(g - (g/288)*288)*32;
  int t = threadIdx.x;
  int l = t&63; int w = rfl(t>>6);
  int ln = l&15, q = l>>4;
  int grp = w>>1, c2w = w&1;
  const f16* db0 = dscT + (size_t)b*HW*NC + c2w*32 + q*8;
  int gibase = b*9*HW + pbase + grp*16 + ln;
  float4 wvq[3]; ushort4 avq[3];
  uint4 G[3][4]; uint4 W2[2][8];
  v4f acc[8];
  #pragma unroll
  for (int nt=0;nt<8;nt++) acc[nt] = (v4f){0.f,0.f,0.f,0.f};
  auto gatherTo = [&](uint4* Gd, const ushort4& av, int s){
    const f16* d0 = db0 + (s&1)*64;
    Gd[0] = *(const uint4*)(d0 + (int)av.x*NC);
    Gd[1] = *(const uint4*)(d0 + (int)av.y*NC);
    Gd[2] = *(const uint4*)(d0 + (int)av.z*NC);
    Gd[3] = *(const uint4*)(d0 + (int)av.w*NC);
  };
  auto wloadTo = [&](uint4* Wt, int s){
    const f16* wp = wfr + (((s*2 + c2w)*8)*64 + l)*8;
    #pragma unroll
    for (int nt=0;nt<8;nt++) Wt[nt] = *(const uint4*)(wp + nt*512);
  };
  auto mstep = [&](uint4* Gd, const float4& wv, uint4* Wt){
    f16 hx=(f16)wv.x, hy=(f16)wv.y, hz=(f16)wv.z, hw=(f16)wv.w;
    h2v wx2={hx,hx}, wy2={hy,hy}, wz2={hz,hz}, ww2={hw,hw};
    unsigned ga[4],gb[4],gc[4],gd[4],ou[4];
    __builtin_memcpy(ga,&Gd[0],16); __builtin_memcpy(gb,&Gd[1],16);
    __builtin_memcpy(gc,&Gd[2],16); __builtin_memcpy(gd,&Gd[3],16);
    #pragma unroll
    for (int j=0;j<4;j++){
      h2v r = u2h2(ga[j])*wx2; r += u2h2(gb[j])*wy2;
      r += u2h2(gc[j])*wz2;    r += u2h2(gd[j])*ww2;
      unsigned uu; __builtin_memcpy(&uu,&r,4); ou[j]=uu;
    }
    uint4 pk; __builtin_memcpy(&pk,ou,16);
    half8 af; __builtin_memcpy(&af,&pk,16);
    #pragma unroll
    for (int nt=0;nt<8;nt++){
      half8 bw; __builtin_memcpy(&bw,&Wt[nt],16);
      acc[nt] = __builtin_amdgcn_mfma_f32_16x16x32_f16(af, bw, acc[nt], 0,0,0);
    }
  };
  // prologue: coords taps 0..2; gathers steps 0..2; weights steps 0,1
  wvq[0]=wg[gibase];       avq[0]=ad[gibase];
  wvq[1]=wg[gibase+HW];    avq[1]=ad[gibase+HW];
  wvq[2]=wg[gibase+2*HW];  avq[2]=ad[gibase+2*HW];
  gatherTo(G[0], avq[0], 0);
  gatherTo(G[1], avq[0], 1);
  gatherTo(G[2], avq[1], 2);
  wloadTo(W2[0], 0); wloadTo(W2[1], 1);
  #pragma unroll
  for (int s=0;s<18;s++){
    int tp = s>>1;
    mstep(G[s%3], wvq[tp%3], W2[s&1]);
    if (s<15) gatherTo(G[s%3], avq[((s+3)>>1)%3], s+3);
    if (s<16) wloadTo(W2[s&1], s+2);
    if ((s&1)==1 && tp<6){
      wvq[tp%3]=wg[gibase+(tp+3)*HW]; avq[tp%3]=ad[gibase+(tp+3)*HW];
    }
  }
  // cross-wave K-half reduction + store
  if (c2w==1){
    #pragma unroll
    for (int nt=0;nt<8;nt++)
      #pragma unroll
      for (int r=0;r<4;r++) Red[grp][l*33 + nt*4 + r] = acc[nt][r];
  }
  __syncthreads();
  if (c2w==0){
    #pragma unroll
    for (int nt=0;nt<8;nt++){
      float bias = dc_b[nt*16 + ln];
      #pragma unroll
      for (int r=0;r<4;r++){
        int px = pbase + grp*16 + q*4 + r;
        float v = acc[nt][r] + Red[grp][l*33 + nt*4 + r] + bias;
        dc_t[((size_t)b*HW + px)*NC + nt*16 + ln] = v;
      }
    }
  }
}

// ---------------- K7: channel LayerNorm + sigmoid gate + multiply ----------------
__global__ __launch_bounds__(256) void epilogue(const float* __restrict__ dc_t,
    const float* __restrict__ dsc, const float* __restrict__ ln_g,
    const float* __restrict__ ln_b, float* __restrict__ out){
  __shared__ float T[64*129];
  __shared__ float Ps[4*64], Qs[4*64], Ms[64], Rs[64];
  int blk = blockIdx.x;
  int g = (blk>>3) + 72*(blk&7);
  int b = rfl(g/144); int pbase = rfl(g - (g/144)*144)*64;
  int t = threadIdx.x;
  #pragma unroll
  for (int i=0;i<8;i++){
    int idx = i*256 + t; int px = idx>>5, seg = idx&31;
    float4 v = *(const float4*)(dc_t + ((size_t)b*HW + pbase + px)*NC + seg*4);
    float* d = &T[px*129 + seg*4];
    d[0]=v.x; d[1]=v.y; d[2]=v.z; d[3]=v.w;
  }
  __syncthreads();
  int px = t&63, cg = t>>6;
  float s=0.f, ss=0.f;
  #pragma unroll
  for (int i=0;i<32;i++){ float v = T[px*129 + cg*32 + i]; s += v; ss = fmaf(v,v,ss); }
  Ps[cg*64+px] = s; Qs[cg*64+px] = ss;
  __syncthreads();
  if (t<64){
    float S = Ps[px]+Ps[64+px]+Ps[128+px]+Ps[192+px];
    float SS= Qs[px]+Qs[64+px]+Qs[128+px]+Qs[192+px];
    float m = S*(1.f/128.f);
    float var = SS*(1.f/128.f) - m*m;
    Ms[px] = m; Rs[px] = rsqrtf(var + 1e-5f);
  }
  __syncthreads();
  float m = Ms[px], rs = Rs[px];
  #pragma unroll 4
  for (int i=0;i<32;i++){
    int c = cg*32 + i;
    float ln = (T[px*129+c] - m)*rs*ln_g[c] + ln_b[c];
    float attn = 1.f/(1.f+__expf(-ln));
    size_t idx = (size_t)(b*NC+c)*HW + pbase + px;
    out[idx] = dsc[idx]*attn;
  }
}

extern "C" void kernel_launch(void* const* d_in, const int* in_sizes, int n_in,
                              void* d_out, int out_size, void* d_ws, size_t ws_size,
                              hipStream_t stream){
  const float* x    = (const float*)d_in[0];
  const float* dw_w = (const float*)d_in[1];
  const float* dw_b = (const float*)d_in[2];
  const float* pw_w = (const float*)d_in[3];
  const float* pw_b = (const float*)d_in[4];
  const float* off_w= (const float*)d_in[5];
  const float* off_b= (const float*)d_in[6];
  const float* dc_w = (const float*)d_in[7];
  const float* dc_b = (const float*)d_in[8];
  const float* ln_g = (const float*)d_in[9];
  const float* ln_b = (const float*)d_in[10];
  float* out = (float*)d_out;

  float* W    = (float*)d_ws;
  float*   bufA = W;                          // h1, then dsc (NCHW f32)
  float*   bufB = W + 4718592;                // h2, then dc_t (NHWC f32)
  f16*     dscT = (f16*)(W + 9437184);        // NHWC fp16
  float4*  wg   = (float4*)(W + 14155776);
  ushort4* ad   = (ushort4*)(W + 15482880);
  float*   st   = W + 16146432;
  f16*     wpwh = (f16*)(W + 16147456);
  f16*     wobf = (f16*)(W + 16155648);
  f16*     wfr  = (f16*)(W + 16174080);

  prep_weights<<<576, 256, 0, stream>>>(pw_w, off_w, dc_w, wpwh, wobf, wfr);
  dw_conv     <<<18432, 256, 0, stream>>>(x, dw_w, dw_b, bufA);
  pw_mfma     <<<576, 256, 0, stream>>>(bufA, wpwh, pw_b, bufB);
  inorm_stats <<<512, 256, 0, stream>>>(bufB, st);
  make_dsc    <<<1152, 256, 0, stream>>>(bufB, st, bufA, dscT);
  off_mfma    <<<576, 256, 0, stream>>>(dscT, wobf, off_b, wg, ad);
  deform_mfma <<<1152, 256, 0, stream>>>(dscT, wfr, dc_b, wg, ad, bufB);
  epilogue    <<<576, 256, 0, stream>>>(bufB, bufA, ln_g, ln_b, out);
}